// Round 1
// baseline (336.007 us; speedup 1.0000x reference)
//
#include <hip/hip_runtime.h>
#include <math.h>

#define BATCH 16384
#define LBL   512
#define HID   768
#define TR    128

typedef unsigned long long u64;

__device__ __forceinline__ float softplusf(float x){
  return fmaxf(x, 0.0f) + log1pf(expf(-fabsf(x)));
}

// EW[l][j] = sum_k E[l][k] * Wl[j][k]    (grid LBL, block 128)
__global__ __launch_bounds__(128) void k_ew(const float* __restrict__ E, const float* __restrict__ Wl,
                                            float* __restrict__ EW){
  __shared__ float se[HID];
  int l = blockIdx.x;
  for (int k = threadIdx.x; k < HID; k += 128) se[k] = E[(size_t)l*HID + k];
  __syncthreads();
  int j = threadIdx.x;
  const float* wr = Wl + (size_t)j*HID;
  float s = 0.f;
  #pragma unroll 8
  for (int k = 0; k < HID; k++) s = fmaf(se[k], wr[k], s);
  EW[l*TR + j] = s;
}

// G[l][i] = sum_j EW[l][j] * W0[i][128+j]   (grid LBL, block 128)
__global__ __launch_bounds__(128) void k_g(const float* __restrict__ EW, const float* __restrict__ W0,
                                           float* __restrict__ G){
  __shared__ float se[TR];
  int l = blockIdx.x;
  se[threadIdx.x] = EW[l*TR + threadIdx.x];
  __syncthreads();
  int i = threadIdx.x;
  const float* wr = W0 + (size_t)i*256 + 128;
  float s = 0.f;
  #pragma unroll 8
  for (int j = 0; j < 128; j++) s = fmaf(se[j], wr[j], s);
  G[l*TR + i] = s;
}

// M[i][c] = sum_a W0[i][a] * Wt[a][c]   (grid TR, block 256; each thread 3 cols)
__global__ __launch_bounds__(256) void k_m(const float* __restrict__ W0, const float* __restrict__ Wt,
                                           float* __restrict__ M){
  __shared__ float sw[TR];
  int i = blockIdx.x;
  if (threadIdx.x < TR) sw[threadIdx.x] = W0[(size_t)i*256 + threadIdx.x];
  __syncthreads();
  int c = threadIdx.x;
  float a0 = 0.f, a1 = 0.f, a2 = 0.f;
  for (int a = 0; a < 128; a++){
    float w = sw[a];
    const float* r = Wt + (size_t)a*HID;
    a0 = fmaf(w, r[c], a0);
    a1 = fmaf(w, r[c+256], a1);
    a2 = fmaf(w, r[c+512], a2);
  }
  M[(size_t)i*HID + c] = a0;
  M[(size_t)i*HID + c+256] = a1;
  M[(size_t)i*HID + c+512] = a2;
}

// KV[i] = b0[i] + sum_a W0[i][a]*bt[a] + sum_j W0[i][128+j]*bl[j];  also zero ACC
__global__ __launch_bounds__(128) void k_k(const float* __restrict__ W0, const float* __restrict__ bt,
                                           const float* __restrict__ bl, const float* __restrict__ b0,
                                           float* __restrict__ KV, float* __restrict__ ACC){
  int i = threadIdx.x;
  float s = b0[i];
  const float* r = W0 + (size_t)i*256;
  for (int a = 0; a < 128; a++) s = fmaf(r[a], bt[a], s);
  for (int j = 0; j < 128; j++) s = fmaf(r[128+j], bl[j], s);
  KV[i] = s;
  if (i == 0) ACC[0] = 0.f;
}

// bitpack target rows + inverse counts.  grid BATCH/4, block 256 (4 waves, 1 row each)
__global__ __launch_bounds__(256) void k_bits(const int* __restrict__ tgt, u64* __restrict__ bits,
                                              float* __restrict__ inv){
  int w = threadIdx.x >> 6, lane = threadIdx.x & 63;
  int b = blockIdx.x*4 + w;
  const int* row = tgt + (size_t)b*LBL;
  int cnt = 0;
  for (int c = 0; c < 8; c++){
    u64 m = __ballot(row[c*64 + lane] != 0);
    if (lane == 0){ bits[(size_t)b*8 + c] = m; cnt += __popcll(m); }
  }
  if (lane == 0){
    float fc = (float)(cnt < 1 ? 1 : cnt);
    inv[b] = 1.0f / fc;
  }
}

// U = text @ M^T + KV   fp32 tiled GEMM, 64 rows x 128 cols per block, Kc=32
__global__ __launch_bounds__(256) void k_u(const float* __restrict__ A, const float* __restrict__ Bm,
                                           const float* __restrict__ KV, float* __restrict__ U){
  __shared__ float At[32][64];
  __shared__ float Bt[32][128];
  int tid = threadIdx.x;
  int tx = tid & 15, ty = tid >> 4;
  int r0 = blockIdx.x * 64;
  int ar = tid & 63, aseg = tid >> 6;      // a: k-sub aseg*8, 8 floats
  int bn = tid & 127, bseg = tid >> 7;     // b: k-sub bseg*16, 16 floats
  float acc[4][8];
  #pragma unroll
  for (int r = 0; r < 4; r++)
    #pragma unroll
    for (int c = 0; c < 8; c++) acc[r][c] = 0.f;

  const float* Arow = A + (size_t)(r0 + ar)*HID;
  const float* Brow = Bm + (size_t)bn*HID;

  for (int k0 = 0; k0 < HID; k0 += 32){
    float4 a0 = *(const float4*)(Arow + k0 + aseg*8);
    float4 a1 = *(const float4*)(Arow + k0 + aseg*8 + 4);
    float4 b0v = *(const float4*)(Brow + k0 + bseg*16);
    float4 b1v = *(const float4*)(Brow + k0 + bseg*16 + 4);
    float4 b2v = *(const float4*)(Brow + k0 + bseg*16 + 8);
    float4 b3v = *(const float4*)(Brow + k0 + bseg*16 + 12);
    __syncthreads();
    At[aseg*8+0][ar] = a0.x; At[aseg*8+1][ar] = a0.y; At[aseg*8+2][ar] = a0.z; At[aseg*8+3][ar] = a0.w;
    At[aseg*8+4][ar] = a1.x; At[aseg*8+5][ar] = a1.y; At[aseg*8+6][ar] = a1.z; At[aseg*8+7][ar] = a1.w;
    Bt[bseg*16+ 0][bn] = b0v.x; Bt[bseg*16+ 1][bn] = b0v.y; Bt[bseg*16+ 2][bn] = b0v.z; Bt[bseg*16+ 3][bn] = b0v.w;
    Bt[bseg*16+ 4][bn] = b1v.x; Bt[bseg*16+ 5][bn] = b1v.y; Bt[bseg*16+ 6][bn] = b1v.z; Bt[bseg*16+ 7][bn] = b1v.w;
    Bt[bseg*16+ 8][bn] = b2v.x; Bt[bseg*16+ 9][bn] = b2v.y; Bt[bseg*16+10][bn] = b2v.z; Bt[bseg*16+11][bn] = b2v.w;
    Bt[bseg*16+12][bn] = b3v.x; Bt[bseg*16+13][bn] = b3v.y; Bt[bseg*16+14][bn] = b3v.z; Bt[bseg*16+15][bn] = b3v.w;
    __syncthreads();
    #pragma unroll 8
    for (int kk = 0; kk < 32; kk++){
      float a4[4], b8[8];
      *(float4*)a4     = *(const float4*)&At[kk][ty*4];
      *(float4*)&b8[0] = *(const float4*)&Bt[kk][tx*8];
      *(float4*)&b8[4] = *(const float4*)&Bt[kk][tx*8+4];
      #pragma unroll
      for (int r = 0; r < 4; r++)
        #pragma unroll
        for (int c = 0; c < 8; c++) acc[r][c] = fmaf(a4[r], b8[c], acc[r][c]);
    }
  }
  float kv[8];
  #pragma unroll
  for (int c = 0; c < 8; c++) kv[c] = KV[tx*8 + c];
  #pragma unroll
  for (int r = 0; r < 4; r++){
    float o[8];
    #pragma unroll
    for (int c = 0; c < 8; c++) o[c] = acc[r][c] + kv[c];
    *(float4*)(U + (size_t)(r0 + ty*4 + r)*TR + tx*8)     = *(float4*)&o[0];
    *(float4*)(U + (size_t)(r0 + ty*4 + r)*TR + tx*8 + 4) = *(float4*)&o[4];
  }
}

// VP[ls][b][c] = sum over l in split ls of mask[b][l]*G[l][c]
// grid (BATCH/64, 4 colchunks, 2 lsplits), block 64.  lane = sample.
__global__ __launch_bounds__(64) void k_v(const float* __restrict__ G, const u64* __restrict__ bits,
                                          float* __restrict__ VP){
  int lane = threadIdx.x;
  int b  = blockIdx.x*64 + lane;
  int c0 = blockIdx.y*32;
  int ls = blockIdx.z;
  float acc[32];
  #pragma unroll
  for (int c = 0; c < 32; c++) acc[c] = 0.f;
  const u64* bp = bits + (size_t)b*8 + ls*4;
  for (int lc = 0; lc < 4; lc++){
    u64 w = bp[lc];
    int lbase = (ls*4 + lc)*64;
    #pragma unroll 4
    for (int lb = 0; lb < 64; lb++){
      float m = (float)((unsigned)(w >> lb) & 1u);
      const float* gr = G + (size_t)(lbase + lb)*TR + c0;
      #pragma unroll
      for (int c = 0; c < 32; c++) acc[c] = fmaf(m, gr[c], acc[c]);
    }
  }
  float* out = VP + ((size_t)ls*BATCH + b)*TR + c0;
  #pragma unroll
  for (int c = 0; c < 32; c += 4)
    *(float4*)(out + c) = *(float4*)&acc[c];
}

// h0p = relu(U[b] + v), h0n = relu(U[perm[b]] + v),  v = (VP0+VP1)*inv[b]
__global__ __launch_bounds__(256) void k_h0(const float* __restrict__ U, const float* __restrict__ VP,
                                            const float* __restrict__ INV, const int* __restrict__ perm,
                                            float* __restrict__ H0P, float* __restrict__ H0N){
  int i = blockIdx.x*256 + threadIdx.x;        // over BATCH*32 float4 groups
  int b  = i >> 5;
  int c4 = (i & 31) << 2;
  float iv = INV[b];
  int pb = perm[b];
  float4 u  = *(const float4*)(U + (size_t)b*TR + c4);
  float4 un = *(const float4*)(U + (size_t)pb*TR + c4);
  float4 v0 = *(const float4*)(VP + (size_t)b*TR + c4);
  float4 v1 = *(const float4*)(VP + ((size_t)BATCH + b)*TR + c4);
  float4 hp, hn;
  float v;
  v = (v0.x+v1.x)*iv; hp.x = fmaxf(u.x+v,0.f); hn.x = fmaxf(un.x+v,0.f);
  v = (v0.y+v1.y)*iv; hp.y = fmaxf(u.y+v,0.f); hn.y = fmaxf(un.y+v,0.f);
  v = (v0.z+v1.z)*iv; hp.z = fmaxf(u.z+v,0.f); hn.z = fmaxf(un.z+v,0.f);
  v = (v0.w+v1.w)*iv; hp.w = fmaxf(u.w+v,0.f); hn.w = fmaxf(un.w+v,0.f);
  *(float4*)(H0P + (size_t)b*TR + c4) = hp;
  *(float4*)(H0N + (size_t)b*TR + c4) = hn;
}

// h1 = relu(h0 @ W1^T + b1); s = w2.h1 + b2; accumulate softplus(+-s)
// grid (BATCH/64, 2 branches), block 256
__global__ __launch_bounds__(256) void k_h1s(const float* __restrict__ H0P, const float* __restrict__ H0N,
                                             const float* __restrict__ W1, const float* __restrict__ b1,
                                             const float* __restrict__ W2, const float* __restrict__ b2,
                                             float* __restrict__ ACC){
  __shared__ float At[32][64];
  __shared__ float Bt[32][128];
  __shared__ float red[64][17];
  int tid = threadIdx.x;
  int tx = tid & 15, ty = tid >> 4;
  int r0 = blockIdx.x * 64;
  int branch = blockIdx.y;
  const float* A = branch ? H0N : H0P;
  int ar = tid & 63, aseg = tid >> 6;
  int bn = tid & 127, bseg = tid >> 7;
  float acc[4][8];
  #pragma unroll
  for (int r = 0; r < 4; r++)
    #pragma unroll
    for (int c = 0; c < 8; c++) acc[r][c] = 0.f;

  const float* Arow = A + (size_t)(r0 + ar)*TR;
  const float* Brow = W1 + (size_t)bn*TR;

  for (int k0 = 0; k0 < TR; k0 += 32){
    float4 a0 = *(const float4*)(Arow + k0 + aseg*8);
    float4 a1 = *(const float4*)(Arow + k0 + aseg*8 + 4);
    float4 b0v = *(const float4*)(Brow + k0 + bseg*16);
    float4 b1v = *(const float4*)(Brow + k0 + bseg*16 + 4);
    float4 b2v = *(const float4*)(Brow + k0 + bseg*16 + 8);
    float4 b3v = *(const float4*)(Brow + k0 + bseg*16 + 12);
    __syncthreads();
    At[aseg*8+0][ar] = a0.x; At[aseg*8+1][ar] = a0.y; At[aseg*8+2][ar] = a0.z; At[aseg*8+3][ar] = a0.w;
    At[aseg*8+4][ar] = a1.x; At[aseg*8+5][ar] = a1.y; At[aseg*8+6][ar] = a1.z; At[aseg*8+7][ar] = a1.w;
    Bt[bseg*16+ 0][bn] = b0v.x; Bt[bseg*16+ 1][bn] = b0v.y; Bt[bseg*16+ 2][bn] = b0v.z; Bt[bseg*16+ 3][bn] = b0v.w;
    Bt[bseg*16+ 4][bn] = b1v.x; Bt[bseg*16+ 5][bn] = b1v.y; Bt[bseg*16+ 6][bn] = b1v.z; Bt[bseg*16+ 7][bn] = b1v.w;
    Bt[bseg*16+ 8][bn] = b2v.x; Bt[bseg*16+ 9][bn] = b2v.y; Bt[bseg*16+10][bn] = b2v.z; Bt[bseg*16+11][bn] = b2v.w;
    Bt[bseg*16+12][bn] = b3v.x; Bt[bseg*16+13][bn] = b3v.y; Bt[bseg*16+14][bn] = b3v.z; Bt[bseg*16+15][bn] = b3v.w;
    __syncthreads();
    #pragma unroll 8
    for (int kk = 0; kk < 32; kk++){
      float a4[4], b8[8];
      *(float4*)a4     = *(const float4*)&At[kk][ty*4];
      *(float4*)&b8[0] = *(const float4*)&Bt[kk][tx*8];
      *(float4*)&b8[4] = *(const float4*)&Bt[kk][tx*8+4];
      #pragma unroll
      for (int r = 0; r < 4; r++)
        #pragma unroll
        for (int c = 0; c < 8; c++) acc[r][c] = fmaf(a4[r], b8[c], acc[r][c]);
    }
  }
  float w2r[8], b1r[8];
  #pragma unroll
  for (int c = 0; c < 8; c++){ w2r[c] = W2[tx*8+c]; b1r[c] = b1[tx*8+c]; }
  #pragma unroll
  for (int r = 0; r < 4; r++){
    float s = 0.f;
    #pragma unroll
    for (int c = 0; c < 8; c++){
      float h = fmaxf(acc[r][c] + b1r[c], 0.f);
      s = fmaf(w2r[c], h, s);
    }
    red[ty*4+r][tx] = s;
  }
  __syncthreads();
  if (tid < 64){
    float s = b2[0];
    #pragma unroll
    for (int t = 0; t < 16; t++) s += red[tid][t];
    float x = branch ? s : -s;          // neg branch: sp(s); pos branch: sp(-s)
    float val = softplusf(x);
    #pragma unroll
    for (int off = 32; off > 0; off >>= 1) val += __shfl_down(val, off);
    if (tid == 0) atomicAdd(ACC, val);
  }
}

__global__ void k_fin(const float* __restrict__ ACC, float* __restrict__ out){
  out[0] = ACC[0] * (1.0f / (float)BATCH);
}

extern "C" void kernel_launch(void* const* d_in, const int* in_sizes, int n_in,
                              void* d_out, int out_size, void* d_ws, size_t ws_size,
                              hipStream_t stream){
  const float* text = (const float*)d_in[0];
  const float* labe = (const float*)d_in[1];
  const int*   tgt  = (const int*)  d_in[2];
  const int*   perm = (const int*)  d_in[3];
  const float* Wt   = (const float*)d_in[4];
  const float* bt   = (const float*)d_in[5];
  const float* Wl   = (const float*)d_in[6];
  const float* bl   = (const float*)d_in[7];
  const float* W0   = (const float*)d_in[8];
  const float* b0   = (const float*)d_in[9];
  const float* W1   = (const float*)d_in[10];
  const float* b1   = (const float*)d_in[11];
  const float* W2   = (const float*)d_in[12];
  const float* b2   = (const float*)d_in[13];

  char* wsb = (char*)d_ws;
  size_t off = 0;
  auto alloc = [&](size_t bytes){
    size_t r = off;
    off += (bytes + 255) & ~(size_t)255;
    return r;
  };
  float* EW  = (float*)(wsb + alloc((size_t)LBL*TR*4));
  float* G   = (float*)(wsb + alloc((size_t)LBL*TR*4));
  float* MM  = (float*)(wsb + alloc((size_t)TR*HID*4));
  float* KV  = (float*)(wsb + alloc((size_t)TR*4));
  float* ACC = (float*)(wsb + alloc(256));
  u64*  BITS = (u64*)  (wsb + alloc((size_t)BATCH*8*8));
  float* INV = (float*)(wsb + alloc((size_t)BATCH*4));
  float* U   = (float*)(wsb + alloc((size_t)BATCH*TR*4));
  float* VP  = (float*)(wsb + alloc((size_t)2*BATCH*TR*4));
  float* H0P = (float*)(wsb + alloc((size_t)BATCH*TR*4));
  float* H0N = (float*)(wsb + alloc((size_t)BATCH*TR*4));
  (void)ws_size; (void)in_sizes; (void)n_in; (void)out_size;

  k_ew  <<<LBL, 128, 0, stream>>>(labe, Wl, EW);
  k_g   <<<LBL, 128, 0, stream>>>(EW, W0, G);
  k_m   <<<TR, 256, 0, stream>>>(W0, Wt, MM);
  k_k   <<<1, 128, 0, stream>>>(W0, bt, bl, b0, KV, ACC);
  k_bits<<<BATCH/4, 256, 0, stream>>>(tgt, BITS, INV);
  k_u   <<<BATCH/64, 256, 0, stream>>>(text, MM, KV, U);
  k_v   <<<dim3(BATCH/64, 4, 2), 64, 0, stream>>>(G, BITS, VP);
  k_h0  <<<(BATCH*TR/4)/256, 256, 0, stream>>>(U, VP, INV, perm, H0P, H0N);
  k_h1s <<<dim3(BATCH/64, 2), 256, 0, stream>>>(H0P, H0N, W1, b1, W2, b2, ACC);
  k_fin <<<1, 1, 0, stream>>>(ACC, (float*)d_out);
}

// Round 2
// 238.068 us; speedup vs baseline: 1.4114x; 1.4114x over previous
//
#include <hip/hip_runtime.h>
#include <math.h>

#define BATCH 16384
#define LBL   512
#define HID   768
#define TR    128

typedef unsigned long long u64;
typedef __attribute__((ext_vector_type(8))) short short8;
typedef __attribute__((ext_vector_type(4))) float f32x4;

__device__ __forceinline__ unsigned short f2bf(float f){
  unsigned u = __builtin_bit_cast(unsigned, f);
  u += 0x7FFFu + ((u >> 16) & 1u);
  return (unsigned short)(u >> 16);
}
__device__ __forceinline__ float softplusf(float x){
  return fmaxf(x, 0.0f) + log1pf(expf(-fabsf(x)));
}

// ---------------- tiny precompute kernels ----------------

// EW[l][j] = sum_k E[l][k] * Wl[j][k]
__global__ __launch_bounds__(128) void k_ew(const float* __restrict__ E, const float* __restrict__ Wl,
                                            float* __restrict__ EW){
  __shared__ float se[HID];
  int l = blockIdx.x;
  for (int k = threadIdx.x; k < HID; k += 128) se[k] = E[(size_t)l*HID + k];
  __syncthreads();
  int j = threadIdx.x;
  const float* wr = Wl + (size_t)j*HID;
  float s = 0.f;
  #pragma unroll 8
  for (int k = 0; k < HID; k++) s = fmaf(se[k], wr[k], s);
  EW[l*TR + j] = s;
}

// Gt[i][l] = sum_j EW[l][j] * W0[i][128+j]   (bf16, transposed: [128][512])
__global__ __launch_bounds__(128) void k_g(const float* __restrict__ EW, const float* __restrict__ W0,
                                           unsigned short* __restrict__ Gt){
  __shared__ float se[TR];
  int l = blockIdx.x;
  se[threadIdx.x] = EW[l*TR + threadIdx.x];
  __syncthreads();
  int i = threadIdx.x;
  const float* wr = W0 + (size_t)i*256 + 128;
  float s = 0.f;
  #pragma unroll 8
  for (int j = 0; j < 128; j++) s = fmaf(se[j], wr[j], s);
  Gt[(size_t)i*LBL + l] = f2bf(s);
}

// Mbf[i][c] = sum_a W0[i][a] * Wt[a][c]   (bf16, [128][768])
__global__ __launch_bounds__(256) void k_m(const float* __restrict__ W0, const float* __restrict__ Wt,
                                           unsigned short* __restrict__ M){
  __shared__ float sw[TR];
  int i = blockIdx.x;
  if (threadIdx.x < TR) sw[threadIdx.x] = W0[(size_t)i*256 + threadIdx.x];
  __syncthreads();
  int c = threadIdx.x;
  float a0 = 0.f, a1 = 0.f, a2 = 0.f;
  for (int a = 0; a < 128; a++){
    float w = sw[a];
    const float* r = Wt + (size_t)a*HID;
    a0 = fmaf(w, r[c], a0);
    a1 = fmaf(w, r[c+256], a1);
    a2 = fmaf(w, r[c+512], a2);
  }
  M[(size_t)i*HID + c]     = f2bf(a0);
  M[(size_t)i*HID + c+256] = f2bf(a1);
  M[(size_t)i*HID + c+512] = f2bf(a2);
}

// KV[i] = b0[i] + W0a.bt + W0b.bl; zero ACC
__global__ __launch_bounds__(128) void k_k(const float* __restrict__ W0, const float* __restrict__ bt,
                                           const float* __restrict__ bl, const float* __restrict__ b0,
                                           float* __restrict__ KV, float* __restrict__ ACC){
  int i = threadIdx.x;
  float s = b0[i];
  const float* r = W0 + (size_t)i*256;
  for (int a = 0; a < 128; a++) s = fmaf(r[a], bt[a], s);
  for (int j = 0; j < 128; j++) s = fmaf(r[128+j], bl[j], s);
  KV[i] = s;
  if (i == 0) ACC[0] = 0.f;
}

// W1 -> bf16
__global__ __launch_bounds__(256) void k_w1(const float* __restrict__ W1, unsigned short* __restrict__ W1b){
  int i = blockIdx.x*256 + threadIdx.x;
  W1b[i] = f2bf(W1[i]);
}

// bitpack target rows + inverse counts
__global__ __launch_bounds__(256) void k_bits(const int* __restrict__ tgt, u64* __restrict__ bits,
                                              float* __restrict__ inv){
  int w = threadIdx.x >> 6, lane = threadIdx.x & 63;
  int b = blockIdx.x*4 + w;
  const int* row = tgt + (size_t)b*LBL;
  int cnt = 0;
  for (int c = 0; c < 8; c++){
    u64 m = __ballot(row[c*64 + lane] != 0);
    if (lane == 0){ bits[(size_t)b*8 + c] = m; cnt += __popcll(m); }
  }
  if (lane == 0){
    float fc = (float)(cnt < 1 ? 1 : cnt);
    inv[b] = 1.0f / fc;
  }
}

// ---------------- U = text @ M^T + KV  (bf16 MFMA) ----------------
// grid 512 blocks, 256 thr (4 waves 2x2). Tile 32 rows x 128 cols, BK=32.
__global__ __launch_bounds__(256) void k_u2(const float* __restrict__ T, const unsigned short* __restrict__ Mbf,
                                            const float* __restrict__ KV, float* __restrict__ U){
  __shared__ __align__(16) unsigned short As[2][32][32];
  int tid = threadIdx.x;
  int lane = tid & 63, wave = tid >> 6;
  int wy = wave >> 1, wx = wave & 1;
  int m = lane & 15, q = lane >> 4;
  int r0 = blockIdx.x * 32;
  int srow = tid >> 3, sc = (tid & 7) * 4;

  const float* tp = T + (size_t)(r0 + srow)*HID + sc;
  const unsigned short* bp[4];
  #pragma unroll
  for (int ct = 0; ct < 4; ct++)
    bp[ct] = Mbf + (size_t)(wx*64 + ct*16 + m)*HID + q*8;

  f32x4 acc[4] = {{0,0,0,0},{0,0,0,0},{0,0,0,0},{0,0,0,0}};
  float4 rA = *(const float4*)tp;
  short8 bcur[4], bnext[4];
  #pragma unroll
  for (int ct = 0; ct < 4; ct++) bcur[ct] = *(const short8*)bp[ct];

  for (int c = 0; c < 24; c++){
    // write staged chunk c (loaded last iter)
    unsigned short w0 = f2bf(rA.x), w1 = f2bf(rA.y), w2 = f2bf(rA.z), w3 = f2bf(rA.w);
    unsigned short* dst = &As[c&1][srow][sc];
    dst[0]=w0; dst[1]=w1; dst[2]=w2; dst[3]=w3;
    __syncthreads();
    if (c < 23){
      rA = *(const float4*)(tp + (c+1)*32);
      #pragma unroll
      for (int ct = 0; ct < 4; ct++) bnext[ct] = *(const short8*)(bp[ct] + (c+1)*32);
    }
    short8 a = *(const short8*)&As[c&1][wy*16 + m][q*8];
    #pragma unroll
    for (int ct = 0; ct < 4; ct++)
      acc[ct] = __builtin_amdgcn_mfma_f32_16x16x32_bf16(a, bcur[ct], acc[ct], 0, 0, 0);
    #pragma unroll
    for (int ct = 0; ct < 4; ct++) bcur[ct] = bnext[ct];
  }

  float kv[4];
  #pragma unroll
  for (int ct = 0; ct < 4; ct++) kv[ct] = KV[wx*64 + ct*16 + m];
  #pragma unroll
  for (int ct = 0; ct < 4; ct++){
    int col = wx*64 + ct*16 + m;
    #pragma unroll
    for (int r = 0; r < 4; r++){
      int rowg = r0 + wy*16 + q*4 + r;
      U[(size_t)rowg*TR + col] = acc[ct][r] + kv[ct];
    }
  }
}

// ---------------- fused V + h0 + h1 + score + reduce ----------------
// grid 512 blocks, 256 thr (4 waves 2x2). 32 rows per block.
__global__ __launch_bounds__(256) void k_fuse(const float* __restrict__ U, const unsigned short* __restrict__ Gt,
                                              const u64* __restrict__ BITS_, const float* __restrict__ INV,
                                              const int* __restrict__ perm, const unsigned short* __restrict__ W1b,
                                              const float* __restrict__ b1, const float* __restrict__ W2,
                                              const float* __restrict__ b2, float* __restrict__ ACC){
  __shared__ __align__(16) unsigned char bits_s[32*80];
  __shared__ __align__(16) unsigned short h0s[32*136];
  __shared__ float sred[2][32][17];
  __shared__ float invs[32];
  __shared__ int   permS[32];

  int tid = threadIdx.x;
  int lane = tid & 63, wave = tid >> 6;
  int wy = wave >> 1, wx = wave & 1;
  int m = lane & 15, q = lane >> 4;
  int r0 = blockIdx.x * 32;

  // stage bits (32 rows x 64B), inv, perm
  if (tid < 128){
    int row = tid >> 2, seg = tid & 3;
    const int4* src = (const int4*)((const char*)BITS_ + (size_t)(r0+row)*64 + seg*16);
    *(int4*)(bits_s + row*80 + seg*16) = *src;
  } else if (tid < 160){
    invs[tid & 31] = INV[r0 + (tid & 31)];
  } else if (tid < 192){
    permS[tid & 31] = perm[r0 + (tid & 31)];
  }
  __syncthreads();

  // ---- V = mask @ G  (K=512) ----
  f32x4 accV[4] = {{0,0,0,0},{0,0,0,0},{0,0,0,0},{0,0,0,0}};
  const unsigned short* gp[4];
  #pragma unroll
  for (int ct = 0; ct < 4; ct++)
    gp[ct] = Gt + (size_t)(wx*64 + ct*16 + m)*LBL + q*8;
  int arow = (wy*16 + m)*80 + q;
  for (int c = 0; c < 16; c++){
    unsigned bb = bits_s[arow + c*4];
    short8 a;
    #pragma unroll
    for (int j = 0; j < 8; j++) a[j] = (short)(((bb >> j) & 1u) ? 0x3F80 : 0);
    #pragma unroll
    for (int ct = 0; ct < 4; ct++){
      short8 b = *(const short8*)(gp[ct] + c*32);
      accV[ct] = __builtin_amdgcn_mfma_f32_16x16x32_bf16(a, b, accV[ct], 0, 0, 0);
    }
  }

  // ---- h0 for both branches (registers) ----
  unsigned short h0pv[16], h0nv[16];
  #pragma unroll
  for (int ct = 0; ct < 4; ct++){
    int col = wx*64 + ct*16 + m;
    #pragma unroll
    for (int r = 0; r < 4; r++){
      int rowl = wy*16 + q*4 + r;
      float iv = invs[rowl];
      float v = accV[ct][r] * iv;
      float up = U[(size_t)(r0 + rowl)*TR + col];
      float un = U[(size_t)permS[rowl]*TR + col];
      h0pv[ct*4+r] = f2bf(fmaxf(up + v, 0.f));
      h0nv[ct*4+r] = f2bf(fmaxf(un + v, 0.f));
    }
  }

  // preload tail weights
  float w2c[4], b1c[4];
  #pragma unroll
  for (int ct = 0; ct < 4; ct++){
    int col = wx*64 + ct*16 + m;
    w2c[ct] = W2[col];
    b1c[ct] = b1[col];
  }
  float b2v = b2[0];
  float total = 0.f;

  for (int br = 0; br < 2; br++){
    __syncthreads();   // protect h0s / sred from previous iteration's readers
    #pragma unroll
    for (int ct = 0; ct < 4; ct++){
      int col = wx*64 + ct*16 + m;
      #pragma unroll
      for (int r = 0; r < 4; r++){
        int rowl = wy*16 + q*4 + r;
        h0s[rowl*136 + col] = br ? h0nv[ct*4+r] : h0pv[ct*4+r];
      }
    }
    __syncthreads();
    // h1 = relu(h0 @ W1^T + b1), K=128
    f32x4 accH[4] = {{0,0,0,0},{0,0,0,0},{0,0,0,0},{0,0,0,0}};
    #pragma unroll
    for (int kc = 0; kc < 4; kc++){
      short8 a = *(const short8*)&h0s[(wy*16 + m)*136 + kc*32 + q*8];
      #pragma unroll
      for (int ct = 0; ct < 4; ct++){
        short8 b = *(const short8*)(W1b + (size_t)(wx*64 + ct*16 + m)*TR + kc*32 + q*8);
        accH[ct] = __builtin_amdgcn_mfma_f32_16x16x32_bf16(a, b, accH[ct], 0, 0, 0);
      }
    }
    // s partials
    #pragma unroll
    for (int r = 0; r < 4; r++){
      float sp = 0.f;
      #pragma unroll
      for (int ct = 0; ct < 4; ct++)
        sp = fmaf(w2c[ct], fmaxf(accH[ct][r] + b1c[ct], 0.f), sp);
      sred[wx][wy*16 + q*4 + r][m] = sp;
    }
    __syncthreads();
    if (tid < 32){
      float s = b2v;
      #pragma unroll
      for (int x = 0; x < 2; x++)
        for (int n = 0; n < 16; n++) s += sred[x][tid][n];
      total += br ? softplusf(s) : softplusf(-s);
    }
  }

  if (tid < 32){
    #pragma unroll
    for (int off = 16; off > 0; off >>= 1) total += __shfl_down(total, off);
    if (tid == 0) atomicAdd(ACC, total);
  }
}

__global__ void k_fin(const float* __restrict__ ACC, float* __restrict__ out){
  out[0] = ACC[0] * (1.0f / (float)BATCH);
}

extern "C" void kernel_launch(void* const* d_in, const int* in_sizes, int n_in,
                              void* d_out, int out_size, void* d_ws, size_t ws_size,
                              hipStream_t stream){
  const float* text = (const float*)d_in[0];
  const float* labe = (const float*)d_in[1];
  const int*   tgt  = (const int*)  d_in[2];
  const int*   perm = (const int*)  d_in[3];
  const float* Wt   = (const float*)d_in[4];
  const float* bt   = (const float*)d_in[5];
  const float* Wl   = (const float*)d_in[6];
  const float* bl   = (const float*)d_in[7];
  const float* W0   = (const float*)d_in[8];
  const float* b0   = (const float*)d_in[9];
  const float* W1   = (const float*)d_in[10];
  const float* b1   = (const float*)d_in[11];
  const float* W2   = (const float*)d_in[12];
  const float* b2   = (const float*)d_in[13];

  char* wsb = (char*)d_ws;
  size_t off = 0;
  auto alloc = [&](size_t bytes){
    size_t r = off;
    off += (bytes + 255) & ~(size_t)255;
    return r;
  };
  float*          EW  = (float*)         (wsb + alloc((size_t)LBL*TR*4));
  unsigned short* GT  = (unsigned short*)(wsb + alloc((size_t)TR*LBL*2));
  unsigned short* MBF = (unsigned short*)(wsb + alloc((size_t)TR*HID*2));
  float*          KV  = (float*)         (wsb + alloc((size_t)TR*4));
  float*          ACC = (float*)         (wsb + alloc(256));
  unsigned short* W1B = (unsigned short*)(wsb + alloc((size_t)TR*TR*2));
  u64*            BITS= (u64*)           (wsb + alloc((size_t)BATCH*8*8));
  float*          INV = (float*)         (wsb + alloc((size_t)BATCH*4));
  float*          U   = (float*)         (wsb + alloc((size_t)BATCH*TR*4));
  (void)ws_size; (void)in_sizes; (void)n_in; (void)out_size;

  k_ew  <<<LBL, 128, 0, stream>>>(labe, Wl, EW);
  k_g   <<<LBL, 128, 0, stream>>>(EW, W0, GT);
  k_m   <<<TR, 256, 0, stream>>>(W0, Wt, MBF);
  k_k   <<<1, 128, 0, stream>>>(W0, bt, bl, b0, KV, ACC);
  k_w1  <<<TR*TR/256, 256, 0, stream>>>(W1, W1B);
  k_bits<<<BATCH/4, 256, 0, stream>>>(tgt, BITS, INV);
  k_u2  <<<BATCH/32, 256, 0, stream>>>(text, MBF, KV, U);
  k_fuse<<<BATCH/32, 256, 0, stream>>>(U, GT, BITS, INV, perm, W1B, b1, W2, b2, ACC);
  k_fin <<<1, 1, 0, stream>>>(ACC, (float*)d_out);
}

// Round 3
// 209.305 us; speedup vs baseline: 1.6053x; 1.1374x over previous
//
#include <hip/hip_runtime.h>
#include <math.h>

#define BATCH 16384
#define LBL   512
#define HID   768
#define TR    128

typedef unsigned long long u64;
typedef unsigned short ushort_t;
typedef __attribute__((ext_vector_type(8))) short short8;
typedef __attribute__((ext_vector_type(4))) float f32x4;

__device__ __forceinline__ ushort_t f2bf(float f){
  unsigned u = __builtin_bit_cast(unsigned, f);
  u += 0x7FFFu + ((u >> 16) & 1u);
  return (ushort_t)(u >> 16);
}
__device__ __forceinline__ float bf2f(ushort_t h){
  unsigned u = ((unsigned)h) << 16;
  return __builtin_bit_cast(float, u);
}
__device__ __forceinline__ float softplusf(float x){
  return fmaxf(x, 0.0f) + log1pf(expf(-fabsf(x)));
}

// ============ one setup kernel: ew+g | m+w1 | biases | bitpack ============
// blocks 0..63    : EW+G for 8 labels each  -> Gt bf16 [128][512]
// blocks 64..191  : M row (bi-64) + W1 row convert
// block 192       : KV + ACC zero
// blocks 193..4288: bitpack 4 target rows each
__global__ __launch_bounds__(256) void k_setup(
    const float* __restrict__ labe, const float* __restrict__ Wl,
    const float* __restrict__ W0,   const float* __restrict__ Wt,
    const float* __restrict__ bt,   const float* __restrict__ bl,
    const float* __restrict__ b0,   const float* __restrict__ W1,
    const int* __restrict__ tgt,
    ushort_t* __restrict__ Gt, ushort_t* __restrict__ MBF, ushort_t* __restrict__ W1B,
    float* __restrict__ KV, float* __restrict__ ACC,
    u64* __restrict__ bits, float* __restrict__ inv){
  __shared__ __align__(16) char smem[28672];
  int bi = blockIdx.x;
  int t = threadIdx.x;

  if (bi < 64){
    int l0 = bi * 8;
    float* sE  = (float*)smem;            // [8][768]
    float* sEW = (float*)(smem + 24576);  // [8][128]
    const float4* src = (const float4*)(labe + (size_t)l0*HID);
    float4* dst4 = (float4*)sE;
    for (int i = t; i < 1536; i += 256) dst4[i] = src[i];
    __syncthreads();
    int j = t & 127, g = t >> 7;          // g in {0,1}, 4 labels each
    {
      const float* wr = Wl + (size_t)j*HID;
      const float* e0 = sE + (g*4+0)*HID;
      const float* e1 = sE + (g*4+1)*HID;
      const float* e2 = sE + (g*4+2)*HID;
      const float* e3 = sE + (g*4+3)*HID;
      float s0=0.f,s1=0.f,s2=0.f,s3=0.f;
      #pragma unroll 4
      for (int k = 0; k < HID; k++){
        float w = wr[k];
        s0 = fmaf(e0[k], w, s0); s1 = fmaf(e1[k], w, s1);
        s2 = fmaf(e2[k], w, s2); s3 = fmaf(e3[k], w, s3);
      }
      sEW[(g*4+0)*TR + j] = s0; sEW[(g*4+1)*TR + j] = s1;
      sEW[(g*4+2)*TR + j] = s2; sEW[(g*4+3)*TR + j] = s3;
    }
    __syncthreads();
    {
      const float* wr = W0 + (size_t)j*256 + 128;
      const float* e0 = sEW + (g*4+0)*TR;
      const float* e1 = sEW + (g*4+1)*TR;
      const float* e2 = sEW + (g*4+2)*TR;
      const float* e3 = sEW + (g*4+3)*TR;
      float s0=0.f,s1=0.f,s2=0.f,s3=0.f;
      #pragma unroll 4
      for (int k = 0; k < TR; k++){
        float w = wr[k];
        s0 = fmaf(e0[k], w, s0); s1 = fmaf(e1[k], w, s1);
        s2 = fmaf(e2[k], w, s2); s3 = fmaf(e3[k], w, s3);
      }
      ushort_t* gdst = Gt + (size_t)j*LBL + l0 + g*4;
      gdst[0] = f2bf(s0); gdst[1] = f2bf(s1); gdst[2] = f2bf(s2); gdst[3] = f2bf(s3);
    }
  } else if (bi < 192){
    int i = bi - 64;
    float* sw = (float*)smem;             // [128]
    if (t < TR) sw[t] = W0[(size_t)i*256 + t];
    if (t < 128) W1B[i*128 + t] = f2bf(W1[i*128 + t]);
    __syncthreads();
    int c = t;
    float a0=0.f, a1=0.f, a2=0.f;
    for (int a = 0; a < 128; a++){
      float w = sw[a];
      const float* r = Wt + (size_t)a*HID;
      a0 = fmaf(w, r[c], a0);
      a1 = fmaf(w, r[c+256], a1);
      a2 = fmaf(w, r[c+512], a2);
    }
    MBF[(size_t)i*HID + c]     = f2bf(a0);
    MBF[(size_t)i*HID + c+256] = f2bf(a1);
    MBF[(size_t)i*HID + c+512] = f2bf(a2);
  } else if (bi == 192){
    if (t < TR){
      float s = b0[t];
      const float* r = W0 + (size_t)t*256;
      for (int a = 0; a < 128; a++) s = fmaf(r[a], bt[a], s);
      for (int a = 0; a < 128; a++) s = fmaf(r[128+a], bl[a], s);
      KV[t] = s;
    }
    if (t == 0) ACC[0] = 0.f;
  } else {
    int w = t >> 6, lane = t & 63;
    int b = (bi - 193)*4 + w;
    const int* row = tgt + (size_t)b*LBL;
    int cnt = 0;
    for (int c = 0; c < 8; c++){
      u64 m = __ballot(row[c*64 + lane] != 0);
      if (lane == 0){ bits[(size_t)b*8 + c] = m; cnt += __popcll(m); }
    }
    if (lane == 0) inv[b] = 1.0f / (float)(cnt < 1 ? 1 : cnt);
  }
}

// ============ U = text @ M^T + KV -> bf16 ============
// grid 512, 256 thr (4 waves 2x2). Tile 32x128, BK=64, dual LDS double-buffer.
__global__ __launch_bounds__(256) void k_u2(const float* __restrict__ T, const ushort_t* __restrict__ Mbf,
                                            const float* __restrict__ KV, ushort_t* __restrict__ U){
  __shared__ __align__(16) ushort_t As[2][32][72];   // row, k (+8 pad)
  __shared__ __align__(16) ushort_t Bs[2][128][72];  // col, k (+8 pad)
  int tid = threadIdx.x;
  int lane = tid & 63, wave = tid >> 6;
  int wy = wave >> 1, wx = wave & 1;
  int m = lane & 15, q = lane >> 4;
  int r0 = blockIdx.x * 32;

  int arow = tid >> 3, ak = (tid & 7) * 8;     // A: 32 rows x 8 k each
  int bcol = tid >> 1, bk = (tid & 1) * 32;    // B: 128 cols x 32 k each

  const float*    ap = T   + (size_t)(r0 + arow)*HID + ak;
  const ushort_t* bp = Mbf + (size_t)bcol*HID + bk;

  float4 ra0 = *(const float4*)(ap);
  float4 ra1 = *(const float4*)(ap + 4);
  short8 rb0 = *(const short8*)(bp);
  short8 rb1 = *(const short8*)(bp + 8);
  short8 rb2 = *(const short8*)(bp + 16);
  short8 rb3 = *(const short8*)(bp + 24);

  f32x4 acc[4] = {{0,0,0,0},{0,0,0,0},{0,0,0,0},{0,0,0,0}};

  for (int c = 0; c < 12; c++){
    int buf = c & 1;
    short8 av;
    av[0] = (short)f2bf(ra0.x); av[1] = (short)f2bf(ra0.y);
    av[2] = (short)f2bf(ra0.z); av[3] = (short)f2bf(ra0.w);
    av[4] = (short)f2bf(ra1.x); av[5] = (short)f2bf(ra1.y);
    av[6] = (short)f2bf(ra1.z); av[7] = (short)f2bf(ra1.w);
    *(short8*)&As[buf][arow][ak]       = av;
    *(short8*)&Bs[buf][bcol][bk]       = rb0;
    *(short8*)&Bs[buf][bcol][bk + 8]   = rb1;
    *(short8*)&Bs[buf][bcol][bk + 16]  = rb2;
    *(short8*)&Bs[buf][bcol][bk + 24]  = rb3;
    __syncthreads();
    if (c < 11){
      const float* apn = ap + (c+1)*64;
      ra0 = *(const float4*)(apn);
      ra1 = *(const float4*)(apn + 4);
      const ushort_t* bpn = bp + (c+1)*64;
      rb0 = *(const short8*)(bpn);
      rb1 = *(const short8*)(bpn + 8);
      rb2 = *(const short8*)(bpn + 16);
      rb3 = *(const short8*)(bpn + 24);
    }
    #pragma unroll
    for (int kc = 0; kc < 2; kc++){
      short8 a = *(const short8*)&As[buf][wy*16 + m][kc*32 + q*8];
      #pragma unroll
      for (int ct = 0; ct < 4; ct++){
        short8 b = *(const short8*)&Bs[buf][wx*64 + ct*16 + m][kc*32 + q*8];
        acc[ct] = __builtin_amdgcn_mfma_f32_16x16x32_bf16(a, b, acc[ct], 0, 0, 0);
      }
    }
  }

  float kv[4];
  #pragma unroll
  for (int ct = 0; ct < 4; ct++) kv[ct] = KV[wx*64 + ct*16 + m];
  #pragma unroll
  for (int ct = 0; ct < 4; ct++){
    int col = wx*64 + ct*16 + m;
    #pragma unroll
    for (int r = 0; r < 4; r++){
      int rowg = r0 + wy*16 + q*4 + r;
      U[(size_t)rowg*TR + col] = f2bf(acc[ct][r] + kv[ct]);
    }
  }
}

// ============ fused V + h0(both) + h1(both) + score + reduce ============
// grid 512, 256 thr (4 waves 2x2), 32 samples per block.
__global__ __launch_bounds__(256) void k_fuse(const ushort_t* __restrict__ U, const ushort_t* __restrict__ Gt,
                                              const u64* __restrict__ BITS_, const float* __restrict__ INV,
                                              const int* __restrict__ perm, const ushort_t* __restrict__ W1b,
                                              const float* __restrict__ b1, const float* __restrict__ W2,
                                              const float* __restrict__ b2, float* __restrict__ ACC){
  __shared__ __align__(16) unsigned char bits_s[32*80];
  __shared__ __align__(16) ushort_t h0s[64][136];    // rows 0-31 pos, 32-63 neg
  __shared__ float sred[2][2][32][17];               // [wx][half][row][m]
  __shared__ float invs[32];
  __shared__ int   permS[32];

  int tid = threadIdx.x;
  int lane = tid & 63, wave = tid >> 6;
  int wy = wave >> 1, wx = wave & 1;
  int m = lane & 15, q = lane >> 4;
  int r0 = blockIdx.x * 32;

  if (tid < 128){
    int row = tid >> 2, seg = tid & 3;
    const int4* src = (const int4*)((const char*)BITS_ + (size_t)(r0+row)*64 + seg*16);
    *(int4*)(bits_s + row*80 + seg*16) = *src;
  } else if (tid < 160){
    invs[tid & 31] = INV[r0 + (tid & 31)];
  } else if (tid < 192){
    permS[tid & 31] = perm[r0 + (tid & 31)];
  }
  __syncthreads();

  // ---- V = mask @ G (K=512), mask bits expanded in-register ----
  f32x4 accV[4] = {{0,0,0,0},{0,0,0,0},{0,0,0,0},{0,0,0,0}};
  const ushort_t* gp[4];
  #pragma unroll
  for (int ct = 0; ct < 4; ct++)
    gp[ct] = Gt + (size_t)(wx*64 + ct*16 + m)*LBL + q*8;
  int arow = (wy*16 + m)*80 + q;
  for (int c = 0; c < 16; c++){
    unsigned bb = bits_s[arow + c*4];
    short8 a;
    #pragma unroll
    for (int j = 0; j < 8; j++) a[j] = (short)(((bb >> j) & 1u) ? 0x3F80 : 0);
    #pragma unroll
    for (int ct = 0; ct < 4; ct++){
      short8 b = *(const short8*)(gp[ct] + c*32);
      accV[ct] = __builtin_amdgcn_mfma_f32_16x16x32_bf16(a, b, accV[ct], 0, 0, 0);
    }
  }

  // ---- h0 both branches -> LDS ----
  #pragma unroll
  for (int ct = 0; ct < 4; ct++){
    int col = wx*64 + ct*16 + m;
    #pragma unroll
    for (int r = 0; r < 4; r++){
      int rowl = wy*16 + q*4 + r;
      float v = accV[ct][r] * invs[rowl];
      float up = bf2f(U[(size_t)(r0 + rowl)*TR + col]);
      float un = bf2f(U[(size_t)permS[rowl]*TR + col]);
      h0s[rowl][col]      = f2bf(fmaxf(up + v, 0.f));
      h0s[32 + rowl][col] = f2bf(fmaxf(un + v, 0.f));
    }
  }
  __syncthreads();

  // ---- h1 both branches (K=128) + score partials ----
  float w2c[4], b1c[4];
  #pragma unroll
  for (int ct = 0; ct < 4; ct++){
    int col = wx*64 + ct*16 + m;
    w2c[ct] = W2[col];
    b1c[ct] = b1[col];
  }
  float b2v = b2[0];

  #pragma unroll
  for (int half = 0; half < 2; half++){
    f32x4 accH[4] = {{0,0,0,0},{0,0,0,0},{0,0,0,0},{0,0,0,0}};
    #pragma unroll
    for (int kc = 0; kc < 4; kc++){
      short8 a = *(const short8*)&h0s[half*32 + wy*16 + m][kc*32 + q*8];
      #pragma unroll
      for (int ct = 0; ct < 4; ct++){
        short8 b = *(const short8*)(W1b + (size_t)(wx*64 + ct*16 + m)*TR + kc*32 + q*8);
        accH[ct] = __builtin_amdgcn_mfma_f32_16x16x32_bf16(a, b, accH[ct], 0, 0, 0);
      }
    }
    #pragma unroll
    for (int r = 0; r < 4; r++){
      float sp = 0.f;
      #pragma unroll
      for (int ct = 0; ct < 4; ct++)
        sp = fmaf(w2c[ct], fmaxf(accH[ct][r] + b1c[ct], 0.f), sp);
      sred[wx][half][wy*16 + q*4 + r][m] = sp;
    }
  }
  __syncthreads();

  if (tid < 64){
    int half = tid >> 5, row = tid & 31;
    float s = b2v;
    #pragma unroll
    for (int x = 0; x < 2; x++)
      #pragma unroll
      for (int n = 0; n < 16; n++) s += sred[x][half][row][n];
    float val = half ? softplusf(s) : softplusf(-s);
    #pragma unroll
    for (int off = 32; off > 0; off >>= 1) val += __shfl_down(val, off);
    if (tid == 0) atomicAdd(ACC, val);
  }
}

__global__ void k_fin(const float* __restrict__ ACC, float* __restrict__ out){
  out[0] = ACC[0] * (1.0f / (float)BATCH);
}

extern "C" void kernel_launch(void* const* d_in, const int* in_sizes, int n_in,
                              void* d_out, int out_size, void* d_ws, size_t ws_size,
                              hipStream_t stream){
  const float* text = (const float*)d_in[0];
  const float* labe = (const float*)d_in[1];
  const int*   tgt  = (const int*)  d_in[2];
  const int*   perm = (const int*)  d_in[3];
  const float* Wt   = (const float*)d_in[4];
  const float* bt   = (const float*)d_in[5];
  const float* Wl   = (const float*)d_in[6];
  const float* bl   = (const float*)d_in[7];
  const float* W0   = (const float*)d_in[8];
  const float* b0   = (const float*)d_in[9];
  const float* W1   = (const float*)d_in[10];
  const float* b1   = (const float*)d_in[11];
  const float* W2   = (const float*)d_in[12];
  const float* b2   = (const float*)d_in[13];

  char* wsb = (char*)d_ws;
  size_t off = 0;
  auto alloc = [&](size_t bytes){
    size_t r = off;
    off += (bytes + 255) & ~(size_t)255;
    return r;
  };
  ushort_t* GT  = (ushort_t*)(wsb + alloc((size_t)TR*LBL*2));
  ushort_t* MBF = (ushort_t*)(wsb + alloc((size_t)TR*HID*2));
  ushort_t* W1B = (ushort_t*)(wsb + alloc((size_t)TR*TR*2));
  float*    KV  = (float*)   (wsb + alloc((size_t)TR*4));
  float*    ACC = (float*)   (wsb + alloc(256));
  u64*      BITS= (u64*)     (wsb + alloc((size_t)BATCH*8*8));
  float*    INV = (float*)   (wsb + alloc((size_t)BATCH*4));
  ushort_t* U   = (ushort_t*)(wsb + alloc((size_t)BATCH*TR*2));
  (void)ws_size; (void)in_sizes; (void)n_in; (void)out_size;

  k_setup<<<4289, 256, 0, stream>>>(labe, Wl, W0, Wt, bt, bl, b0, W1, tgt,
                                    GT, MBF, W1B, KV, ACC, BITS, INV);
  k_u2   <<<BATCH/32, 256, 0, stream>>>(text, MBF, KV, U);
  k_fuse <<<BATCH/32, 256, 0, stream>>>(U, GT, BITS, INV, perm, W1B, b1, W2, b2, ACC);
  k_fin  <<<1, 1, 0, stream>>>(ACC, (float*)d_out);
}

// Round 4
// 199.617 us; speedup vs baseline: 1.6833x; 1.0485x over previous
//
#include <hip/hip_runtime.h>
#include <math.h>

#define BATCH 16384
#define LBL   512
#define HID   768
#define TR    128

typedef unsigned long long u64;
typedef unsigned short ushort_t;
typedef __attribute__((ext_vector_type(8))) short short8;
typedef __attribute__((ext_vector_type(4))) float f32x4;

__device__ __forceinline__ ushort_t f2bf(float f){
  unsigned u = __builtin_bit_cast(unsigned, f);
  u += 0x7FFFu + ((u >> 16) & 1u);
  return (ushort_t)(u >> 16);
}
__device__ __forceinline__ float bf2f(ushort_t h){
  unsigned u = ((unsigned)h) << 16;
  return __builtin_bit_cast(float, u);
}
__device__ __forceinline__ float softplusf(float x){
  return fmaxf(x, 0.0f) + log1pf(expf(-fabsf(x)));
}

// ============ one setup kernel ============
// blocks 0..7     : EW=labe@Wl^T then G=EW@W0b^T via MFMA, 64 labels each -> Gt bf16 [128][512]
// blocks 8..135   : M row (bi-8) fp32 + W1 row convert
// block 136       : KV + ACC zero
// blocks 137..4232: bitpack 4 target rows each
__global__ __launch_bounds__(256) void k_setup(
    const float* __restrict__ labe, const float* __restrict__ Wl,
    const float* __restrict__ W0,   const float* __restrict__ Wt,
    const float* __restrict__ bt,   const float* __restrict__ bl,
    const float* __restrict__ b0,   const float* __restrict__ W1,
    const int* __restrict__ tgt,
    ushort_t* __restrict__ Gt, ushort_t* __restrict__ MBF, ushort_t* __restrict__ W1B,
    float* __restrict__ KV, float* __restrict__ ACC,
    u64* __restrict__ bits, float* __restrict__ inv){
  __shared__ __align__(16) char smem[45056];
  int bi = blockIdx.x;
  int t = threadIdx.x;

  if (bi < 8){
    ushort_t (*As)[72]   = (ushort_t(*)[72])smem;            //  9216 B
    ushort_t (*Bs)[72]   = (ushort_t(*)[72])(smem + 9216);   // 18432 B
    ushort_t (*EWs)[136] = (ushort_t(*)[136])(smem + 27648); // 17408 B
    int l0 = bi * 64;
    int lane = t & 63, wave = t >> 6;
    int wy = wave >> 1, wx = wave & 1;
    int m = lane & 15, q = lane >> 4;
    int arow = t >> 2, ak = (t & 3) * 16;
    int bcol = t >> 1, bk = (t & 1) * 32;

    // ---- stage 1: EW = labe @ Wl^T  (64x128, K=768) ----
    f32x4 acc[2][4] = {};
    const float* apb = labe + (size_t)(l0 + arow)*HID + ak;
    const float* bpb = Wl + (size_t)bcol*HID + bk;
    for (int c = 0; c < 12; c++){
      const float* ap = apb + c*64;
      float4 a0 = *(const float4*)(ap);
      float4 a1 = *(const float4*)(ap + 4);
      float4 a2 = *(const float4*)(ap + 8);
      float4 a3 = *(const float4*)(ap + 12);
      const float* bp = bpb + c*64;
      float4 b0v = *(const float4*)(bp);
      float4 b1v = *(const float4*)(bp + 4);
      float4 b2v = *(const float4*)(bp + 8);
      float4 b3v = *(const float4*)(bp + 12);
      float4 b4v = *(const float4*)(bp + 16);
      float4 b5v = *(const float4*)(bp + 20);
      float4 b6v = *(const float4*)(bp + 24);
      float4 b7v = *(const float4*)(bp + 28);
      __syncthreads();
      ushort_t* ad = &As[arow][ak];
      ad[0]=f2bf(a0.x); ad[1]=f2bf(a0.y); ad[2]=f2bf(a0.z); ad[3]=f2bf(a0.w);
      ad[4]=f2bf(a1.x); ad[5]=f2bf(a1.y); ad[6]=f2bf(a1.z); ad[7]=f2bf(a1.w);
      ad[8]=f2bf(a2.x); ad[9]=f2bf(a2.y); ad[10]=f2bf(a2.z); ad[11]=f2bf(a2.w);
      ad[12]=f2bf(a3.x); ad[13]=f2bf(a3.y); ad[14]=f2bf(a3.z); ad[15]=f2bf(a3.w);
      ushort_t* bd = &Bs[bcol][bk];
      bd[0]=f2bf(b0v.x); bd[1]=f2bf(b0v.y); bd[2]=f2bf(b0v.z); bd[3]=f2bf(b0v.w);
      bd[4]=f2bf(b1v.x); bd[5]=f2bf(b1v.y); bd[6]=f2bf(b1v.z); bd[7]=f2bf(b1v.w);
      bd[8]=f2bf(b2v.x); bd[9]=f2bf(b2v.y); bd[10]=f2bf(b2v.z); bd[11]=f2bf(b2v.w);
      bd[12]=f2bf(b3v.x); bd[13]=f2bf(b3v.y); bd[14]=f2bf(b3v.z); bd[15]=f2bf(b3v.w);
      bd[16]=f2bf(b4v.x); bd[17]=f2bf(b4v.y); bd[18]=f2bf(b4v.z); bd[19]=f2bf(b4v.w);
      bd[20]=f2bf(b5v.x); bd[21]=f2bf(b5v.y); bd[22]=f2bf(b5v.z); bd[23]=f2bf(b5v.w);
      bd[24]=f2bf(b6v.x); bd[25]=f2bf(b6v.y); bd[26]=f2bf(b6v.z); bd[27]=f2bf(b6v.w);
      bd[28]=f2bf(b7v.x); bd[29]=f2bf(b7v.y); bd[30]=f2bf(b7v.z); bd[31]=f2bf(b7v.w);
      __syncthreads();
      #pragma unroll
      for (int kc = 0; kc < 2; kc++){
        short8 bfr[4];
        #pragma unroll
        for (int ct = 0; ct < 4; ct++)
          bfr[ct] = *(const short8*)&Bs[wx*64 + ct*16 + m][kc*32 + q*8];
        #pragma unroll
        for (int rt = 0; rt < 2; rt++){
          short8 afr = *(const short8*)&As[wy*32 + rt*16 + m][kc*32 + q*8];
          #pragma unroll
          for (int ct = 0; ct < 4; ct++)
            acc[rt][ct] = __builtin_amdgcn_mfma_f32_16x16x32_bf16(afr, bfr[ct], acc[rt][ct], 0, 0, 0);
        }
      }
    }
    // EW -> LDS (A-layout for stage 2)
    __syncthreads();
    #pragma unroll
    for (int rt = 0; rt < 2; rt++)
      #pragma unroll
      for (int ct = 0; ct < 4; ct++)
        #pragma unroll
        for (int r = 0; r < 4; r++)
          EWs[wy*32 + rt*16 + q*4 + r][wx*64 + ct*16 + m] = f2bf(acc[rt][ct][r]);

    // ---- stage 2: G = EW @ W0b^T  (64x128, K=128) ----
    f32x4 accG[2][4] = {};
    for (int c = 0; c < 2; c++){
      const float* bp = W0 + (size_t)bcol*256 + 128 + c*64 + bk;
      float4 b0v = *(const float4*)(bp);
      float4 b1v = *(const float4*)(bp + 4);
      float4 b2v = *(const float4*)(bp + 8);
      float4 b3v = *(const float4*)(bp + 12);
      float4 b4v = *(const float4*)(bp + 16);
      float4 b5v = *(const float4*)(bp + 20);
      float4 b6v = *(const float4*)(bp + 24);
      float4 b7v = *(const float4*)(bp + 28);
      __syncthreads();
      ushort_t* bd = &Bs[bcol][bk];
      bd[0]=f2bf(b0v.x); bd[1]=f2bf(b0v.y); bd[2]=f2bf(b0v.z); bd[3]=f2bf(b0v.w);
      bd[4]=f2bf(b1v.x); bd[5]=f2bf(b1v.y); bd[6]=f2bf(b1v.z); bd[7]=f2bf(b1v.w);
      bd[8]=f2bf(b2v.x); bd[9]=f2bf(b2v.y); bd[10]=f2bf(b2v.z); bd[11]=f2bf(b2v.w);
      bd[12]=f2bf(b3v.x); bd[13]=f2bf(b3v.y); bd[14]=f2bf(b3v.z); bd[15]=f2bf(b3v.w);
      bd[16]=f2bf(b4v.x); bd[17]=f2bf(b4v.y); bd[18]=f2bf(b4v.z); bd[19]=f2bf(b4v.w);
      bd[20]=f2bf(b5v.x); bd[21]=f2bf(b5v.y); bd[22]=f2bf(b5v.z); bd[23]=f2bf(b5v.w);
      bd[24]=f2bf(b6v.x); bd[25]=f2bf(b6v.y); bd[26]=f2bf(b6v.z); bd[27]=f2bf(b6v.w);
      bd[28]=f2bf(b7v.x); bd[29]=f2bf(b7v.y); bd[30]=f2bf(b7v.z); bd[31]=f2bf(b7v.w);
      __syncthreads();
      #pragma unroll
      for (int kc = 0; kc < 2; kc++){
        short8 bfr[4];
        #pragma unroll
        for (int ct = 0; ct < 4; ct++)
          bfr[ct] = *(const short8*)&Bs[wx*64 + ct*16 + m][kc*32 + q*8];
        #pragma unroll
        for (int rt = 0; rt < 2; rt++){
          short8 afr = *(const short8*)&EWs[wy*32 + rt*16 + m][c*64 + kc*32 + q*8];
          #pragma unroll
          for (int ct = 0; ct < 4; ct++)
            accG[rt][ct] = __builtin_amdgcn_mfma_f32_16x16x32_bf16(afr, bfr[ct], accG[rt][ct], 0, 0, 0);
        }
      }
    }
    // G -> LDS transposed [col i][label] then coalesced write to Gt
    __syncthreads();
    ushort_t (*GTs)[72] = Bs;
    #pragma unroll
    for (int rt = 0; rt < 2; rt++)
      #pragma unroll
      for (int ct = 0; ct < 4; ct++)
        #pragma unroll
        for (int r = 0; r < 4; r++)
          GTs[wx*64 + ct*16 + m][wy*32 + rt*16 + q*4 + r] = f2bf(accG[rt][ct][r]);
    __syncthreads();
    int gi = t >> 1, half = t & 1;
    const ushort_t* srcp = &GTs[gi][half*32];
    ushort_t* dstp = Gt + (size_t)gi*LBL + l0 + half*32;
    #pragma unroll
    for (int s = 0; s < 4; s++)
      *(short8*)(dstp + s*8) = *(const short8*)(srcp + s*8);
  } else if (bi < 136){
    int i = bi - 8;
    float* sw = (float*)smem;
    if (t < TR) sw[t] = W0[(size_t)i*256 + t];
    if (t < 128) W1B[i*128 + t] = f2bf(W1[i*128 + t]);
    __syncthreads();
    int c = t;
    float a0=0.f, a1=0.f, a2=0.f;
    for (int a = 0; a < 128; a++){
      float w = sw[a];
      const float* r = Wt + (size_t)a*HID;
      a0 = fmaf(w, r[c], a0);
      a1 = fmaf(w, r[c+256], a1);
      a2 = fmaf(w, r[c+512], a2);
    }
    MBF[(size_t)i*HID + c]     = f2bf(a0);
    MBF[(size_t)i*HID + c+256] = f2bf(a1);
    MBF[(size_t)i*HID + c+512] = f2bf(a2);
  } else if (bi == 136){
    if (t < TR){
      float s = b0[t];
      const float* r = W0 + (size_t)t*256;
      for (int a = 0; a < 128; a++) s = fmaf(r[a], bt[a], s);
      for (int a = 0; a < 128; a++) s = fmaf(r[128+a], bl[a], s);
      KV[t] = s;
    }
    if (t == 0) ACC[0] = 0.f;
  } else {
    int w = t >> 6, lane = t & 63;
    int b = (bi - 137)*4 + w;
    const int* row = tgt + (size_t)b*LBL;
    int cnt = 0;
    for (int c = 0; c < 8; c++){
      u64 m = __ballot(row[c*64 + lane] != 0);
      if (lane == 0){ bits[(size_t)b*8 + c] = m; cnt += __popcll(m); }
    }
    if (lane == 0) inv[b] = 1.0f / (float)(cnt < 1 ? 1 : cnt);
  }
}

// ============ U = text @ M^T + KV -> bf16 ============
// grid 512, 256 thr (4 waves 2x2). Tile 32x128, BK=64, dual LDS double-buffer.
__global__ __launch_bounds__(256) void k_u2(const float* __restrict__ T, const ushort_t* __restrict__ Mbf,
                                            const float* __restrict__ KV, ushort_t* __restrict__ U){
  __shared__ __align__(16) ushort_t As[2][32][72];
  __shared__ __align__(16) ushort_t Bs[2][128][72];
  int tid = threadIdx.x;
  int lane = tid & 63, wave = tid >> 6;
  int wy = wave >> 1, wx = wave & 1;
  int m = lane & 15, q = lane >> 4;
  int r0 = blockIdx.x * 32;

  int arow = tid >> 3, ak = (tid & 7) * 8;
  int bcol = tid >> 1, bk = (tid & 1) * 32;

  const float*    ap = T   + (size_t)(r0 + arow)*HID + ak;
  const ushort_t* bp = Mbf + (size_t)bcol*HID + bk;

  float4 ra0 = *(const float4*)(ap);
  float4 ra1 = *(const float4*)(ap + 4);
  short8 rb0 = *(const short8*)(bp);
  short8 rb1 = *(const short8*)(bp + 8);
  short8 rb2 = *(const short8*)(bp + 16);
  short8 rb3 = *(const short8*)(bp + 24);

  f32x4 acc[4] = {{0,0,0,0},{0,0,0,0},{0,0,0,0},{0,0,0,0}};

  for (int c = 0; c < 12; c++){
    int buf = c & 1;
    short8 av;
    av[0] = (short)f2bf(ra0.x); av[1] = (short)f2bf(ra0.y);
    av[2] = (short)f2bf(ra0.z); av[3] = (short)f2bf(ra0.w);
    av[4] = (short)f2bf(ra1.x); av[5] = (short)f2bf(ra1.y);
    av[6] = (short)f2bf(ra1.z); av[7] = (short)f2bf(ra1.w);
    *(short8*)&As[buf][arow][ak]       = av;
    *(short8*)&Bs[buf][bcol][bk]       = rb0;
    *(short8*)&Bs[buf][bcol][bk + 8]   = rb1;
    *(short8*)&Bs[buf][bcol][bk + 16]  = rb2;
    *(short8*)&Bs[buf][bcol][bk + 24]  = rb3;
    __syncthreads();
    if (c < 11){
      const float* apn = ap + (c+1)*64;
      ra0 = *(const float4*)(apn);
      ra1 = *(const float4*)(apn + 4);
      const ushort_t* bpn = bp + (c+1)*64;
      rb0 = *(const short8*)(bpn);
      rb1 = *(const short8*)(bpn + 8);
      rb2 = *(const short8*)(bpn + 16);
      rb3 = *(const short8*)(bpn + 24);
    }
    #pragma unroll
    for (int kc = 0; kc < 2; kc++){
      short8 a = *(const short8*)&As[buf][wy*16 + m][kc*32 + q*8];
      #pragma unroll
      for (int ct = 0; ct < 4; ct++){
        short8 b = *(const short8*)&Bs[buf][wx*64 + ct*16 + m][kc*32 + q*8];
        acc[ct] = __builtin_amdgcn_mfma_f32_16x16x32_bf16(a, b, acc[ct], 0, 0, 0);
      }
    }
  }

  float kv[4];
  #pragma unroll
  for (int ct = 0; ct < 4; ct++) kv[ct] = KV[wx*64 + ct*16 + m];
  #pragma unroll
  for (int ct = 0; ct < 4; ct++){
    int col = wx*64 + ct*16 + m;
    #pragma unroll
    for (int r = 0; r < 4; r++){
      int rowg = r0 + wy*16 + q*4 + r;
      U[(size_t)rowg*TR + col] = f2bf(acc[ct][r] + kv[ct]);
    }
  }
}

// ============ fused V + h0(both) + h1(both) + score + reduce ============
__global__ __launch_bounds__(256) void k_fuse(const ushort_t* __restrict__ U, const ushort_t* __restrict__ Gt,
                                              const u64* __restrict__ BITS_, const float* __restrict__ INV,
                                              const int* __restrict__ perm, const ushort_t* __restrict__ W1b,
                                              const float* __restrict__ b1, const float* __restrict__ W2,
                                              const float* __restrict__ b2, float* __restrict__ ACC){
  __shared__ __align__(16) unsigned char bits_s[32*80];
  __shared__ __align__(16) ushort_t h0s[64][136];
  __shared__ float sred[2][2][32][17];
  __shared__ float invs[32];
  __shared__ int   permS[32];

  int tid = threadIdx.x;
  int lane = tid & 63, wave = tid >> 6;
  int wy = wave >> 1, wx = wave & 1;
  int m = lane & 15, q = lane >> 4;
  int r0 = blockIdx.x * 32;

  if (tid < 128){
    int row = tid >> 2, seg = tid & 3;
    const int4* src = (const int4*)((const char*)BITS_ + (size_t)(r0+row)*64 + seg*16);
    *(int4*)(bits_s + row*80 + seg*16) = *src;
  } else if (tid < 160){
    invs[tid & 31] = INV[r0 + (tid & 31)];
  } else if (tid < 192){
    permS[tid & 31] = perm[r0 + (tid & 31)];
  }
  __syncthreads();

  f32x4 accV[4] = {{0,0,0,0},{0,0,0,0},{0,0,0,0},{0,0,0,0}};
  const ushort_t* gp[4];
  #pragma unroll
  for (int ct = 0; ct < 4; ct++)
    gp[ct] = Gt + (size_t)(wx*64 + ct*16 + m)*LBL + q*8;
  int arow = (wy*16 + m)*80 + q;
  for (int c = 0; c < 16; c++){
    unsigned bb = bits_s[arow + c*4];
    short8 a;
    #pragma unroll
    for (int j = 0; j < 8; j++) a[j] = (short)(((bb >> j) & 1u) ? 0x3F80 : 0);
    #pragma unroll
    for (int ct = 0; ct < 4; ct++){
      short8 b = *(const short8*)(gp[ct] + c*32);
      accV[ct] = __builtin_amdgcn_mfma_f32_16x16x32_bf16(a, b, accV[ct], 0, 0, 0);
    }
  }

  #pragma unroll
  for (int ct = 0; ct < 4; ct++){
    int col = wx*64 + ct*16 + m;
    #pragma unroll
    for (int r = 0; r < 4; r++){
      int rowl = wy*16 + q*4 + r;
      float v = accV[ct][r] * invs[rowl];
      float up = bf2f(U[(size_t)(r0 + rowl)*TR + col]);
      float un = bf2f(U[(size_t)permS[rowl]*TR + col]);
      h0s[rowl][col]      = f2bf(fmaxf(up + v, 0.f));
      h0s[32 + rowl][col] = f2bf(fmaxf(un + v, 0.f));
    }
  }
  __syncthreads();

  float w2c[4], b1c[4];
  #pragma unroll
  for (int ct = 0; ct < 4; ct++){
    int col = wx*64 + ct*16 + m;
    w2c[ct] = W2[col];
    b1c[ct] = b1[col];
  }
  float b2v = b2[0];

  #pragma unroll
  for (int half = 0; half < 2; half++){
    f32x4 accH[4] = {{0,0,0,0},{0,0,0,0},{0,0,0,0},{0,0,0,0}};
    #pragma unroll
    for (int kc = 0; kc < 4; kc++){
      short8 a = *(const short8*)&h0s[half*32 + wy*16 + m][kc*32 + q*8];
      #pragma unroll
      for (int ct = 0; ct < 4; ct++){
        short8 b = *(const short8*)(W1b + (size_t)(wx*64 + ct*16 + m)*TR + kc*32 + q*8);
        accH[ct] = __builtin_amdgcn_mfma_f32_16x16x32_bf16(a, b, accH[ct], 0, 0, 0);
      }
    }
    #pragma unroll
    for (int r = 0; r < 4; r++){
      float sp = 0.f;
      #pragma unroll
      for (int ct = 0; ct < 4; ct++)
        sp = fmaf(w2c[ct], fmaxf(accH[ct][r] + b1c[ct], 0.f), sp);
      sred[wx][half][wy*16 + q*4 + r][m] = sp;
    }
  }
  __syncthreads();

  if (tid < 64){
    int half = tid >> 5, row = tid & 31;
    float s = b2v;
    #pragma unroll
    for (int x = 0; x < 2; x++)
      #pragma unroll
      for (int n = 0; n < 16; n++) s += sred[x][half][row][n];
    float val = half ? softplusf(s) : softplusf(-s);
    #pragma unroll
    for (int off = 32; off > 0; off >>= 1) val += __shfl_down(val, off);
    if (tid == 0) atomicAdd(ACC, val);
  }
}

__global__ void k_fin(const float* __restrict__ ACC, float* __restrict__ out){
  out[0] = ACC[0] * (1.0f / (float)BATCH);
}

extern "C" void kernel_launch(void* const* d_in, const int* in_sizes, int n_in,
                              void* d_out, int out_size, void* d_ws, size_t ws_size,
                              hipStream_t stream){
  const float* text = (const float*)d_in[0];
  const float* labe = (const float*)d_in[1];
  const int*   tgt  = (const int*)  d_in[2];
  const int*   perm = (const int*)  d_in[3];
  const float* Wt   = (const float*)d_in[4];
  const float* bt   = (const float*)d_in[5];
  const float* Wl   = (const float*)d_in[6];
  const float* bl   = (const float*)d_in[7];
  const float* W0   = (const float*)d_in[8];
  const float* b0   = (const float*)d_in[9];
  const float* W1   = (const float*)d_in[10];
  const float* b1   = (const float*)d_in[11];
  const float* W2   = (const float*)d_in[12];
  const float* b2   = (const float*)d_in[13];

  char* wsb = (char*)d_ws;
  size_t off = 0;
  auto alloc = [&](size_t bytes){
    size_t r = off;
    off += (bytes + 255) & ~(size_t)255;
    return r;
  };
  ushort_t* GT  = (ushort_t*)(wsb + alloc((size_t)TR*LBL*2));
  ushort_t* MBF = (ushort_t*)(wsb + alloc((size_t)TR*HID*2));
  ushort_t* W1B = (ushort_t*)(wsb + alloc((size_t)TR*TR*2));
  float*    KV  = (float*)   (wsb + alloc((size_t)TR*4));
  float*    ACC = (float*)   (wsb + alloc(256));
  u64*      BITS= (u64*)     (wsb + alloc((size_t)BATCH*8*8));
  float*    INV = (float*)   (wsb + alloc((size_t)BATCH*4));
  ushort_t* U   = (ushort_t*)(wsb + alloc((size_t)BATCH*TR*2));
  (void)ws_size; (void)in_sizes; (void)n_in; (void)out_size;

  k_setup<<<4233, 256, 0, stream>>>(labe, Wl, W0, Wt, bt, bl, b0, W1, tgt,
                                    GT, MBF, W1B, KV, ACC, BITS, INV);
  k_u2   <<<BATCH/32, 256, 0, stream>>>(text, MBF, KV, U);
  k_fuse <<<BATCH/32, 256, 0, stream>>>(U, GT, BITS, INV, perm, W1B, b1, W2, b2, ACC);
  k_fin  <<<1, 1, 0, stream>>>(ACC, (float*)d_out);
}

// Round 5
// 185.348 us; speedup vs baseline: 1.8128x; 1.0770x over previous
//
#include <hip/hip_runtime.h>
#include <math.h>

#define BATCH 16384
#define LBL   512
#define HID   768
#define TR    128

typedef unsigned long long u64;
typedef unsigned short ushort_t;
typedef __attribute__((ext_vector_type(8))) short short8;
typedef __attribute__((ext_vector_type(4))) float f32x4;

__device__ __forceinline__ ushort_t f2bf(float f){
  unsigned u = __builtin_bit_cast(unsigned, f);
  u += 0x7FFFu + ((u >> 16) & 1u);
  return (ushort_t)(u >> 16);
}
__device__ __forceinline__ float bf2f(ushort_t h){
  unsigned u = ((unsigned)h) << 16;
  return __builtin_bit_cast(float, u);
}
__device__ __forceinline__ float softplusf(float x){
  return fmaxf(x, 0.0f) + log1pf(expf(-fabsf(x)));
}
__device__ __forceinline__ void gload_lds16(const void* g, void* l){
  __builtin_amdgcn_global_load_lds((const __attribute__((address_space(1))) void*)g,
                                   (__attribute__((address_space(3))) void*)l, 16, 0, 0);
}

// ============ k_w1: M = W0a@Wt, Q = W0b@Wl (swizzled bf16), W1->bf16, KV, ACC ============
// Swizzle: element (n, k) of a [128 n][768 k] B-matrix stored at ((k>>3)<<10) + (n<<3) + (k&7).
// Chunk kc (64 k's) is then the contiguous 16 KB at elem offset kc*8192 -> global_load_lds ready.
__global__ __launch_bounds__(256) void k_w1(
    const float* __restrict__ W0, const float* __restrict__ Wt, const float* __restrict__ Wl,
    const float* __restrict__ bt, const float* __restrict__ bl, const float* __restrict__ b0,
    const float* __restrict__ W1,
    ushort_t* __restrict__ Msw, ushort_t* __restrict__ Qsw, ushort_t* __restrict__ W1B,
    float* __restrict__ KV, float* __restrict__ ACC){
  __shared__ float sw[TR];
  int bi = blockIdx.x, t = threadIdx.x;
  if (bi < 256){
    int i = bi & 127;
    int isQ = bi >> 7;
    const float* src = isQ ? Wl : Wt;
    ushort_t* dst = isQ ? Qsw : Msw;
    if (t < TR) sw[t] = W0[(size_t)i*256 + isQ*128 + t];
    if (!isQ && t < 128) W1B[i*128 + t] = f2bf(W1[i*128 + t]);
    __syncthreads();
    int c = t;
    float a0 = 0.f, a1 = 0.f, a2 = 0.f;
    #pragma unroll 4
    for (int a = 0; a < 128; a++){
      float w = sw[a];
      const float* r = src + (size_t)a*HID;
      a0 = fmaf(w, r[c], a0);
      a1 = fmaf(w, r[c+256], a1);
      a2 = fmaf(w, r[c+512], a2);
    }
    int c7 = c & 7;
    dst[(((c      )>>3)<<10) + (i<<3) + c7] = f2bf(a0);
    dst[(((c + 256)>>3)<<10) + (i<<3) + c7] = f2bf(a1);
    dst[(((c + 512)>>3)<<10) + (i<<3) + c7] = f2bf(a2);
  } else {
    if (t < TR){
      float s = b0[t];
      const float* r = W0 + (size_t)t*256;
      for (int a = 0; a < 128; a++) s = fmaf(r[a], bt[a], s);
      for (int a = 0; a < 128; a++) s = fmaf(r[128+a], bl[a], s);
      KV[t] = s;
    }
    if (t == 0) ACC[0] = 0.f;
  }
}

// ============ k_phase2: blocks 0..31 G = labe @ Q^T -> Gt[i][l]; blocks 32..2079 bitpack ============
__global__ __launch_bounds__(256) void k_phase2(
    const float* __restrict__ labe, const ushort_t* __restrict__ Qsw,
    const int* __restrict__ tgt,
    ushort_t* __restrict__ Gt, u64* __restrict__ bits, float* __restrict__ inv){
  __shared__ __align__(16) ushort_t Bs[2][8192];   // 2 x 16KB, swizzled chunk mirror
  __shared__ __align__(16) ushort_t As[2][16][72];
  int bi = blockIdx.x, tid = threadIdx.x;
  if (bi < 32){
    int lane = tid & 63, wave = tid >> 6;
    int m = lane & 15, q = lane >> 4;
    int l0 = bi * 16;
    int arow = tid >> 4, a4 = (tid & 15) * 4;
    const float* ap = labe + (size_t)(l0 + arow)*HID + a4;

    float4 ra = *(const float4*)ap;
    {
      const char* gb = (const char*)Qsw;
      char* lb = (char*)&Bs[0][0];
      #pragma unroll
      for (int p = 0; p < 4; p++)
        gload_lds16(gb + p*4096 + tid*16, lb + p*4096 + tid*16);
    }
    f32x4 acc[2] = {{0,0,0,0},{0,0,0,0}};
    for (int c = 0; c < 12; c++){
      int buf = c & 1;
      ushort_t* ad = &As[buf][arow][a4];
      ad[0]=f2bf(ra.x); ad[1]=f2bf(ra.y); ad[2]=f2bf(ra.z); ad[3]=f2bf(ra.w);
      __syncthreads();
      if (c < 11){
        ra = *(const float4*)(ap + (c+1)*64);
        const char* gb = (const char*)Qsw + (size_t)(c+1)*16384;
        char* lb = (char*)&Bs[buf^1][0];
        #pragma unroll
        for (int p = 0; p < 4; p++)
          gload_lds16(gb + p*4096 + tid*16, lb + p*4096 + tid*16);
      }
      #pragma unroll
      for (int kcc = 0; kcc < 2; kcc++){
        short8 a = *(const short8*)&As[buf][m][kcc*32 + q*8];
        #pragma unroll
        for (int ct = 0; ct < 2; ct++){
          int col = wave*32 + ct*16 + m;
          short8 b = *(const short8*)&Bs[buf][(kcc*4 + q)*1024 + col*8];
          acc[ct] = __builtin_amdgcn_mfma_f32_16x16x32_bf16(a, b, acc[ct], 0, 0, 0);
        }
      }
    }
    // transpose epilogue via LDS (overlay on Bs[0], free after last MFMA which used buf 1)
    __syncthreads();
    ushort_t (*GTs)[24] = (ushort_t(*)[24])&Bs[0][0];
    #pragma unroll
    for (int ct = 0; ct < 2; ct++){
      int col = wave*32 + ct*16 + m;
      #pragma unroll
      for (int r = 0; r < 4; r++)
        GTs[col][q*4 + r] = f2bf(acc[ct][r]);
    }
    __syncthreads();
    int gi = tid >> 1, loff = (tid & 1) * 8;
    *(short8*)(Gt + (size_t)gi*LBL + l0 + loff) = *(const short8*)&GTs[gi][loff];
  } else {
    int bi2 = bi - 32;
    int w = tid >> 6, lane = tid & 63;
    int b0r = bi2*8 + w*2;
    const int* row0 = tgt + (size_t)b0r*LBL;
    const int* row1 = row0 + LBL;
    int v0[8], v1[8];
    #pragma unroll
    for (int c = 0; c < 8; c++) v0[c] = row0[c*64 + lane];
    #pragma unroll
    for (int c = 0; c < 8; c++) v1[c] = row1[c*64 + lane];
    int c0 = 0, c1 = 0;
    #pragma unroll
    for (int c = 0; c < 8; c++){
      u64 m0 = __ballot(v0[c] != 0);
      u64 m1 = __ballot(v1[c] != 0);
      if (lane == 0){
        bits[(size_t)b0r*8 + c] = m0;       c0 += __popcll(m0);
        bits[(size_t)(b0r+1)*8 + c] = m1;   c1 += __popcll(m1);
      }
    }
    if (lane == 0){
      inv[b0r]   = 1.0f / (float)(c0 < 1 ? 1 : c0);
      inv[b0r+1] = 1.0f / (float)(c1 < 1 ? 1 : c1);
    }
  }
}

// ============ k_u2: U = text @ M^T + KV -> bf16.  1024 blocks x 16 rows ============
__global__ __launch_bounds__(256) void k_u2(const float* __restrict__ T, const ushort_t* __restrict__ Msw,
                                            const float* __restrict__ KV, ushort_t* __restrict__ U){
  __shared__ __align__(16) ushort_t Bs[2][8192];
  __shared__ __align__(16) ushort_t As[2][16][72];
  int tid = threadIdx.x;
  int lane = tid & 63, wave = tid >> 6;
  int m = lane & 15, q = lane >> 4;
  int r0 = blockIdx.x * 16;
  int arow = tid >> 4, a4 = (tid & 15) * 4;
  const float* ap = T + (size_t)(r0 + arow)*HID + a4;

  float4 ra = *(const float4*)ap;
  {
    const char* gb = (const char*)Msw;
    char* lb = (char*)&Bs[0][0];
    #pragma unroll
    for (int p = 0; p < 4; p++)
      gload_lds16(gb + p*4096 + tid*16, lb + p*4096 + tid*16);
  }
  f32x4 acc[2] = {{0,0,0,0},{0,0,0,0}};
  for (int c = 0; c < 12; c++){
    int buf = c & 1;
    ushort_t* ad = &As[buf][arow][a4];
    ad[0]=f2bf(ra.x); ad[1]=f2bf(ra.y); ad[2]=f2bf(ra.z); ad[3]=f2bf(ra.w);
    __syncthreads();
    if (c < 11){
      ra = *(const float4*)(ap + (c+1)*64);
      const char* gb = (const char*)Msw + (size_t)(c+1)*16384;
      char* lb = (char*)&Bs[buf^1][0];
      #pragma unroll
      for (int p = 0; p < 4; p++)
        gload_lds16(gb + p*4096 + tid*16, lb + p*4096 + tid*16);
    }
    #pragma unroll
    for (int kcc = 0; kcc < 2; kcc++){
      short8 a = *(const short8*)&As[buf][m][kcc*32 + q*8];
      #pragma unroll
      for (int ct = 0; ct < 2; ct++){
        int col = wave*32 + ct*16 + m;
        short8 b = *(const short8*)&Bs[buf][(kcc*4 + q)*1024 + col*8];
        acc[ct] = __builtin_amdgcn_mfma_f32_16x16x32_bf16(a, b, acc[ct], 0, 0, 0);
      }
    }
  }
  #pragma unroll
  for (int ct = 0; ct < 2; ct++){
    int col = wave*32 + ct*16 + m;
    float kv = KV[col];
    #pragma unroll
    for (int r = 0; r < 4; r++)
      U[(size_t)(r0 + q*4 + r)*TR + col] = f2bf(acc[ct][r] + kv);
  }
}

// ============ k_fuse: V + h0(both) + h1(both) + score + reduce.  1024 blocks x 16 rows ============
__global__ __launch_bounds__(256) void k_fuse(const ushort_t* __restrict__ U, const ushort_t* __restrict__ Gt,
                                              const u64* __restrict__ BITS_, const float* __restrict__ INV,
                                              const int* __restrict__ perm, const ushort_t* __restrict__ W1b,
                                              const float* __restrict__ b1, const float* __restrict__ W2,
                                              const float* __restrict__ b2, float* __restrict__ ACC){
  __shared__ __align__(16) unsigned char bits_s[16*80];
  __shared__ __align__(16) ushort_t h0s[32][136];   // 0-15 pos, 16-31 neg
  __shared__ float sred[4][2][16][17];
  __shared__ float invs[16];
  __shared__ int   permS[16];

  int tid = threadIdx.x;
  int lane = tid & 63, wave = tid >> 6;
  int m = lane & 15, q = lane >> 4;
  int r0 = blockIdx.x * 16;

  if (tid < 64){
    int row = tid >> 2, seg = tid & 3;
    const int4* src = (const int4*)((const char*)BITS_ + (size_t)(r0+row)*64 + seg*16);
    *(int4*)(bits_s + row*80 + seg*16) = *src;
  } else if (tid < 80){
    invs[tid - 64] = INV[r0 + tid - 64];
  } else if (tid < 96){
    permS[tid - 80] = perm[r0 + tid - 80];
  }
  __syncthreads();

  // hoist U loads (cover their latency with the V-GEMM below)
  float up[2][4], un[2][4];
  #pragma unroll
  for (int ct = 0; ct < 2; ct++){
    int col = wave*32 + ct*16 + m;
    #pragma unroll
    for (int r = 0; r < 4; r++){
      int rowl = q*4 + r;
      up[ct][r] = bf2f(U[(size_t)(r0 + rowl)*TR + col]);
      un[ct][r] = bf2f(U[(size_t)permS[rowl]*TR + col]);
    }
  }

  // V = mask @ G (K=512), Gt prefetch 1-deep
  f32x4 accV[2] = {{0,0,0,0},{0,0,0,0}};
  const ushort_t* gp[2];
  #pragma unroll
  for (int ct = 0; ct < 2; ct++)
    gp[ct] = Gt + (size_t)(wave*32 + ct*16 + m)*LBL + q*8;
  short8 bcur[2], bnext[2];
  #pragma unroll
  for (int ct = 0; ct < 2; ct++) bcur[ct] = *(const short8*)(gp[ct]);
  int abase = m*80 + q;
  for (int c = 0; c < 16; c++){
    if (c < 15){
      #pragma unroll
      for (int ct = 0; ct < 2; ct++) bnext[ct] = *(const short8*)(gp[ct] + (c+1)*32);
    }
    unsigned bb = bits_s[abase + c*4];
    short8 a;
    #pragma unroll
    for (int j = 0; j < 8; j++) a[j] = (short)(((bb >> j) & 1u) ? 0x3F80 : 0);
    #pragma unroll
    for (int ct = 0; ct < 2; ct++)
      accV[ct] = __builtin_amdgcn_mfma_f32_16x16x32_bf16(a, bcur[ct], accV[ct], 0, 0, 0);
    #pragma unroll
    for (int ct = 0; ct < 2; ct++) bcur[ct] = bnext[ct];
  }

  // h0 both branches -> LDS
  #pragma unroll
  for (int ct = 0; ct < 2; ct++){
    int col = wave*32 + ct*16 + m;
    #pragma unroll
    for (int r = 0; r < 4; r++){
      int rowl = q*4 + r;
      float v = accV[ct][r] * invs[rowl];
      h0s[rowl][col]      = f2bf(fmaxf(up[ct][r] + v, 0.f));
      h0s[16 + rowl][col] = f2bf(fmaxf(un[ct][r] + v, 0.f));
    }
  }
  __syncthreads();

  float w2c[2], b1c[2];
  #pragma unroll
  for (int ct = 0; ct < 2; ct++){
    int col = wave*32 + ct*16 + m;
    w2c[ct] = W2[col];
    b1c[ct] = b1[col];
  }
  float b2v = b2[0];

  #pragma unroll
  for (int half = 0; half < 2; half++){
    f32x4 accH[2] = {{0,0,0,0},{0,0,0,0}};
    #pragma unroll
    for (int kc = 0; kc < 4; kc++){
      short8 a = *(const short8*)&h0s[half*16 + m][kc*32 + q*8];
      #pragma unroll
      for (int ct = 0; ct < 2; ct++){
        short8 b = *(const short8*)(W1b + (size_t)(wave*32 + ct*16 + m)*TR + kc*32 + q*8);
        accH[ct] = __builtin_amdgcn_mfma_f32_16x16x32_bf16(a, b, accH[ct], 0, 0, 0);
      }
    }
    #pragma unroll
    for (int r = 0; r < 4; r++){
      float sp = 0.f;
      #pragma unroll
      for (int ct = 0; ct < 2; ct++)
        sp = fmaf(w2c[ct], fmaxf(accH[ct][r] + b1c[ct], 0.f), sp);
      sred[wave][half][q*4 + r][m] = sp;
    }
  }
  __syncthreads();

  if (tid < 32){
    int half = tid >> 4, row = tid & 15;
    float s = b2v;
    #pragma unroll
    for (int wx = 0; wx < 4; wx++)
      #pragma unroll
      for (int n = 0; n < 16; n++) s += sred[wx][half][row][n];
    float val = half ? softplusf(s) : softplusf(-s);
    #pragma unroll
    for (int off = 16; off > 0; off >>= 1) val += __shfl_down(val, off);
    if (tid == 0) atomicAdd(ACC, val);
  }
}

__global__ void k_fin(const float* __restrict__ ACC, float* __restrict__ out){
  out[0] = ACC[0] * (1.0f / (float)BATCH);
}

extern "C" void kernel_launch(void* const* d_in, const int* in_sizes, int n_in,
                              void* d_out, int out_size, void* d_ws, size_t ws_size,
                              hipStream_t stream){
  const float* text = (const float*)d_in[0];
  const float* labe = (const float*)d_in[1];
  const int*   tgt  = (const int*)  d_in[2];
  const int*   perm = (const int*)  d_in[3];
  const float* Wt   = (const float*)d_in[4];
  const float* bt   = (const float*)d_in[5];
  const float* Wl   = (const float*)d_in[6];
  const float* bl   = (const float*)d_in[7];
  const float* W0   = (const float*)d_in[8];
  const float* b0   = (const float*)d_in[9];
  const float* W1   = (const float*)d_in[10];
  const float* b1   = (const float*)d_in[11];
  const float* W2   = (const float*)d_in[12];
  const float* b2   = (const float*)d_in[13];

  char* wsb = (char*)d_ws;
  size_t off = 0;
  auto alloc = [&](size_t bytes){
    size_t r = off;
    off += (bytes + 255) & ~(size_t)255;
    return r;
  };
  ushort_t* MSW = (ushort_t*)(wsb + alloc((size_t)TR*HID*2));
  ushort_t* QSW = (ushort_t*)(wsb + alloc((size_t)TR*HID*2));
  ushort_t* GT  = (ushort_t*)(wsb + alloc((size_t)TR*LBL*2));
  ushort_t* W1B = (ushort_t*)(wsb + alloc((size_t)TR*TR*2));
  float*    KV  = (float*)   (wsb + alloc((size_t)TR*4));
  float*    ACC = (float*)   (wsb + alloc(256));
  u64*      BITS= (u64*)     (wsb + alloc((size_t)BATCH*8*8));
  float*    INV = (float*)   (wsb + alloc((size_t)BATCH*4));
  ushort_t* U   = (ushort_t*)(wsb + alloc((size_t)BATCH*TR*2));
  (void)ws_size; (void)in_sizes; (void)n_in; (void)out_size;

  k_w1    <<<257, 256, 0, stream>>>(W0, Wt, Wl, bt, bl, b0, W1, MSW, QSW, W1B, KV, ACC);
  k_phase2<<<2080, 256, 0, stream>>>(labe, QSW, tgt, GT, BITS, INV);
  k_u2    <<<BATCH/16, 256, 0, stream>>>(text, MSW, KV, U);
  k_fuse  <<<BATCH/16, 256, 0, stream>>>(U, GT, BITS, INV, perm, W1B, b1, W2, b2, ACC);
  k_fin   <<<1, 1, 0, stream>>>(ACC, (float*)d_out);
}

// Round 6
// 172.791 us; speedup vs baseline: 1.9446x; 1.0727x over previous
//
#include <hip/hip_runtime.h>
#include <math.h>

#define BATCH 16384
#define LBL   512
#define HID   768
#define TR    128

typedef unsigned long long u64;
typedef unsigned short ushort_t;
typedef __attribute__((ext_vector_type(8))) short short8;
typedef __attribute__((ext_vector_type(4))) float f32x4;

__device__ __forceinline__ ushort_t f2bf(float f){
  unsigned u = __builtin_bit_cast(unsigned, f);
  u += 0x7FFFu + ((u >> 16) & 1u);
  return (ushort_t)(u >> 16);
}
__device__ __forceinline__ float bf2f(ushort_t h){
  unsigned u = ((unsigned)h) << 16;
  return __builtin_bit_cast(float, u);
}
__device__ __forceinline__ float softplusf(float x){
  return fmaxf(x, 0.0f) + log1pf(expf(-fabsf(x)));
}
__device__ __forceinline__ void gload_lds16(const void* g, void* l){
  __builtin_amdgcn_global_load_lds((const __attribute__((address_space(1))) void*)g,
                                   (__attribute__((address_space(3))) void*)l, 16, 0, 0);
}

// ============ k1: M = W0a@Wt, Q = W0b@Wl (swizzled bf16), W1->bf16, KV, zero out ============
// Swizzle: element (n, k) of a [128 n][768 k] B-matrix at ((k>>3)<<10) + (n<<3) + (k&7);
// chunk kc (64 k) = contiguous 16 KB at elem offset kc*8192 -> global_load_lds ready.
__global__ __launch_bounds__(256) void k1(
    const float* __restrict__ W0, const float* __restrict__ Wt, const float* __restrict__ Wl,
    const float* __restrict__ bt, const float* __restrict__ bl, const float* __restrict__ b0,
    const float* __restrict__ W1,
    ushort_t* __restrict__ Msw, ushort_t* __restrict__ Qsw, ushort_t* __restrict__ W1B,
    float* __restrict__ KV, float* __restrict__ out){
  __shared__ float sw[TR];
  int bi = blockIdx.x, t = threadIdx.x;
  if (bi < 256){
    int i = bi & 127;
    int isQ = bi >> 7;
    const float* src = isQ ? Wl : Wt;
    ushort_t* dst = isQ ? Qsw : Msw;
    if (t < TR) sw[t] = W0[(size_t)i*256 + isQ*128 + t];
    if (!isQ && t < 128) W1B[i*128 + t] = f2bf(W1[i*128 + t]);
    __syncthreads();
    int c = t;
    float a0 = 0.f, a1 = 0.f, a2 = 0.f;
    #pragma unroll 8
    for (int a = 0; a < 128; a++){
      float w = sw[a];
      const float* r = src + (size_t)a*HID;
      a0 = fmaf(w, r[c], a0);
      a1 = fmaf(w, r[c+256], a1);
      a2 = fmaf(w, r[c+512], a2);
    }
    int c7 = c & 7;
    dst[(((c      )>>3)<<10) + (i<<3) + c7] = f2bf(a0);
    dst[(((c + 256)>>3)<<10) + (i<<3) + c7] = f2bf(a1);
    dst[(((c + 512)>>3)<<10) + (i<<3) + c7] = f2bf(a2);
  } else {
    if (t < TR){
      float s = b0[t];
      const float* r = W0 + (size_t)t*256;
      for (int a = 0; a < 128; a++) s = fmaf(r[a], bt[a], s);
      for (int a = 0; a < 128; a++) s = fmaf(r[128+a], bl[a], s);
      KV[t] = s;
    }
    if (t == 0) out[0] = 0.f;
  }
}

// ============ k2: blocks 0..31 G = labe@Q^T -> Gt[i][l]; blocks 32..1055 U = text@M^T + KV ============
__global__ __launch_bounds__(256) void k2(
    const float* __restrict__ labe, const ushort_t* __restrict__ Qsw,
    const float* __restrict__ T,    const ushort_t* __restrict__ Msw,
    const float* __restrict__ KV,
    ushort_t* __restrict__ Gt, ushort_t* __restrict__ U){
  __shared__ __align__(16) ushort_t Bs[2][8192];
  __shared__ __align__(16) ushort_t As[2][16][72];
  int bi = blockIdx.x, tid = threadIdx.x;
  int lane = tid & 63, wave = tid >> 6;
  int m = lane & 15, q = lane >> 4;
  int arow = tid >> 4, a4 = (tid & 15) * 4;

  if (bi < 32){
    // ---- G-GEMM: 16 labels per block, K=768 ----
    int l0 = bi * 16;
    const float* ap = labe + (size_t)(l0 + arow)*HID + a4;
    float4 ra = *(const float4*)ap;
    {
      const char* gb = (const char*)Qsw;
      char* lb = (char*)&Bs[0][0];
      #pragma unroll
      for (int p = 0; p < 4; p++)
        gload_lds16(gb + p*4096 + tid*16, lb + p*4096 + tid*16);
    }
    f32x4 acc[2] = {{0,0,0,0},{0,0,0,0}};
    for (int c = 0; c < 12; c++){
      int buf = c & 1;
      ushort_t* ad = &As[buf][arow][a4];
      ad[0]=f2bf(ra.x); ad[1]=f2bf(ra.y); ad[2]=f2bf(ra.z); ad[3]=f2bf(ra.w);
      __syncthreads();
      if (c < 11){
        ra = *(const float4*)(ap + (c+1)*64);
        const char* gb = (const char*)Qsw + (size_t)(c+1)*16384;
        char* lb = (char*)&Bs[buf^1][0];
        #pragma unroll
        for (int p = 0; p < 4; p++)
          gload_lds16(gb + p*4096 + tid*16, lb + p*4096 + tid*16);
      }
      #pragma unroll
      for (int kcc = 0; kcc < 2; kcc++){
        short8 a = *(const short8*)&As[buf][m][kcc*32 + q*8];
        #pragma unroll
        for (int ct = 0; ct < 2; ct++){
          int col = wave*32 + ct*16 + m;
          short8 b = *(const short8*)&Bs[buf][(kcc*4 + q)*1024 + col*8];
          acc[ct] = __builtin_amdgcn_mfma_f32_16x16x32_bf16(a, b, acc[ct], 0, 0, 0);
        }
      }
    }
    // transpose epilogue via LDS -> coalesced Gt write
    __syncthreads();
    ushort_t (*GTs)[24] = (ushort_t(*)[24])&Bs[0][0];
    #pragma unroll
    for (int ct = 0; ct < 2; ct++){
      int col = wave*32 + ct*16 + m;
      #pragma unroll
      for (int r = 0; r < 4; r++)
        GTs[col][q*4 + r] = f2bf(acc[ct][r]);
    }
    __syncthreads();
    int gi = tid >> 1, loff = (tid & 1) * 8;
    *(short8*)(Gt + (size_t)gi*LBL + l0 + loff) = *(const short8*)&GTs[gi][loff];
  } else {
    // ---- U-GEMM: 16 rows per block, K=768 ----
    int r0 = (bi - 32) * 16;
    const float* ap = T + (size_t)(r0 + arow)*HID + a4;
    float4 ra = *(const float4*)ap;
    {
      const char* gb = (const char*)Msw;
      char* lb = (char*)&Bs[0][0];
      #pragma unroll
      for (int p = 0; p < 4; p++)
        gload_lds16(gb + p*4096 + tid*16, lb + p*4096 + tid*16);
    }
    f32x4 acc[2] = {{0,0,0,0},{0,0,0,0}};
    for (int c = 0; c < 12; c++){
      int buf = c & 1;
      ushort_t* ad = &As[buf][arow][a4];
      ad[0]=f2bf(ra.x); ad[1]=f2bf(ra.y); ad[2]=f2bf(ra.z); ad[3]=f2bf(ra.w);
      __syncthreads();
      if (c < 11){
        ra = *(const float4*)(ap + (c+1)*64);
        const char* gb = (const char*)Msw + (size_t)(c+1)*16384;
        char* lb = (char*)&Bs[buf^1][0];
        #pragma unroll
        for (int p = 0; p < 4; p++)
          gload_lds16(gb + p*4096 + tid*16, lb + p*4096 + tid*16);
      }
      #pragma unroll
      for (int kcc = 0; kcc < 2; kcc++){
        short8 a = *(const short8*)&As[buf][m][kcc*32 + q*8];
        #pragma unroll
        for (int ct = 0; ct < 2; ct++){
          int col = wave*32 + ct*16 + m;
          short8 b = *(const short8*)&Bs[buf][(kcc*4 + q)*1024 + col*8];
          acc[ct] = __builtin_amdgcn_mfma_f32_16x16x32_bf16(a, b, acc[ct], 0, 0, 0);
        }
      }
    }
    #pragma unroll
    for (int ct = 0; ct < 2; ct++){
      int col = wave*32 + ct*16 + m;
      float kv = KV[col];
      #pragma unroll
      for (int r = 0; r < 4; r++)
        U[(size_t)(r0 + q*4 + r)*TR + col] = f2bf(acc[ct][r] + kv);
    }
  }
}

// ============ k3: in-block bitpack + V + h0(both) + h1(both) + score -> scaled atomic ============
__global__ __launch_bounds__(256) void k3(const ushort_t* __restrict__ U, const ushort_t* __restrict__ Gt,
                                          const int* __restrict__ tgt, const int* __restrict__ perm,
                                          const ushort_t* __restrict__ W1b, const float* __restrict__ b1,
                                          const float* __restrict__ W2, const float* __restrict__ b2,
                                          float* __restrict__ out){
  __shared__ __align__(16) u64 bits_s8[16*10];      // 80-byte pitch per row
  __shared__ __align__(16) ushort_t h0s[32][136];   // 0-15 pos, 16-31 neg
  __shared__ float sred[4][2][16][17];
  __shared__ float invs[16];
  __shared__ int   permS[16];

  int tid = threadIdx.x;
  int lane = tid & 63, wave = tid >> 6;
  int m = lane & 15, q = lane >> 4;
  int r0 = blockIdx.x * 16;

  if (tid < 16) permS[tid] = perm[r0 + tid];

  // bitpack own 16 rows: wave w handles rows w*4..w*4+3
  #pragma unroll
  for (int rr = 0; rr < 4; rr++){
    int row = wave*4 + rr;
    const int* rp = tgt + (size_t)(r0 + row)*LBL;
    int v[8];
    #pragma unroll
    for (int c = 0; c < 8; c++) v[c] = rp[c*64 + lane];
    int cnt = 0;
    #pragma unroll
    for (int c = 0; c < 8; c++){
      u64 mm = __ballot(v[c] != 0);
      if (lane == 0){ bits_s8[row*10 + c] = mm; cnt += __popcll(mm); }
    }
    if (lane == 0) invs[row] = 1.0f / (float)(cnt < 1 ? 1 : cnt);
  }
  __syncthreads();

  // hoist U loads (latency covered by V-GEMM)
  float up[2][4], un[2][4];
  #pragma unroll
  for (int ct = 0; ct < 2; ct++){
    int col = wave*32 + ct*16 + m;
    #pragma unroll
    for (int r = 0; r < 4; r++){
      int rowl = q*4 + r;
      up[ct][r] = bf2f(U[(size_t)(r0 + rowl)*TR + col]);
      un[ct][r] = bf2f(U[(size_t)permS[rowl]*TR + col]);
    }
  }

  // V = mask @ G (K=512), Gt prefetch 1-deep
  const unsigned char* bits_b = (const unsigned char*)bits_s8;
  f32x4 accV[2] = {{0,0,0,0},{0,0,0,0}};
  const ushort_t* gp[2];
  #pragma unroll
  for (int ct = 0; ct < 2; ct++)
    gp[ct] = Gt + (size_t)(wave*32 + ct*16 + m)*LBL + q*8;
  short8 bcur[2], bnext[2];
  #pragma unroll
  for (int ct = 0; ct < 2; ct++) bcur[ct] = *(const short8*)(gp[ct]);
  int abase = m*80 + q;
  for (int c = 0; c < 16; c++){
    if (c < 15){
      #pragma unroll
      for (int ct = 0; ct < 2; ct++) bnext[ct] = *(const short8*)(gp[ct] + (c+1)*32);
    }
    unsigned bb = bits_b[abase + c*4];
    short8 a;
    #pragma unroll
    for (int j = 0; j < 8; j++) a[j] = (short)(((bb >> j) & 1u) ? 0x3F80 : 0);
    #pragma unroll
    for (int ct = 0; ct < 2; ct++)
      accV[ct] = __builtin_amdgcn_mfma_f32_16x16x32_bf16(a, bcur[ct], accV[ct], 0, 0, 0);
    #pragma unroll
    for (int ct = 0; ct < 2; ct++) bcur[ct] = bnext[ct];
  }

  // h0 both branches -> LDS
  #pragma unroll
  for (int ct = 0; ct < 2; ct++){
    int col = wave*32 + ct*16 + m;
    #pragma unroll
    for (int r = 0; r < 4; r++){
      int rowl = q*4 + r;
      float v = accV[ct][r] * invs[rowl];
      h0s[rowl][col]      = f2bf(fmaxf(up[ct][r] + v, 0.f));
      h0s[16 + rowl][col] = f2bf(fmaxf(un[ct][r] + v, 0.f));
    }
  }
  __syncthreads();

  float w2c[2], b1c[2];
  #pragma unroll
  for (int ct = 0; ct < 2; ct++){
    int col = wave*32 + ct*16 + m;
    w2c[ct] = W2[col];
    b1c[ct] = b1[col];
  }
  float b2v = b2[0];

  #pragma unroll
  for (int half = 0; half < 2; half++){
    f32x4 accH[2] = {{0,0,0,0},{0,0,0,0}};
    #pragma unroll
    for (int kc = 0; kc < 4; kc++){
      short8 a = *(const short8*)&h0s[half*16 + m][kc*32 + q*8];
      #pragma unroll
      for (int ct = 0; ct < 2; ct++){
        short8 b = *(const short8*)(W1b + (size_t)(wave*32 + ct*16 + m)*TR + kc*32 + q*8);
        accH[ct] = __builtin_amdgcn_mfma_f32_16x16x32_bf16(a, b, accH[ct], 0, 0, 0);
      }
    }
    #pragma unroll
    for (int r = 0; r < 4; r++){
      float sp = 0.f;
      #pragma unroll
      for (int ct = 0; ct < 2; ct++)
        sp = fmaf(w2c[ct], fmaxf(accH[ct][r] + b1c[ct], 0.f), sp);
      sred[wave][half][q*4 + r][m] = sp;
    }
  }
  __syncthreads();

  if (tid < 32){
    int half = tid >> 4, row = tid & 15;
    float s = b2v;
    #pragma unroll
    for (int wx = 0; wx < 4; wx++)
      #pragma unroll
      for (int n = 0; n < 16; n++) s += sred[wx][half][row][n];
    float val = half ? softplusf(s) : softplusf(-s);
    #pragma unroll
    for (int off = 16; off > 0; off >>= 1) val += __shfl_down(val, off);
    if (tid == 0) atomicAdd(out, val * (1.0f / (float)BATCH));
  }
}

extern "C" void kernel_launch(void* const* d_in, const int* in_sizes, int n_in,
                              void* d_out, int out_size, void* d_ws, size_t ws_size,
                              hipStream_t stream){
  const float* text = (const float*)d_in[0];
  const float* labe = (const float*)d_in[1];
  const int*   tgt  = (const int*)  d_in[2];
  const int*   perm = (const int*)  d_in[3];
  const float* Wt   = (const float*)d_in[4];
  const float* bt   = (const float*)d_in[5];
  const float* Wl   = (const float*)d_in[6];
  const float* bl   = (const float*)d_in[7];
  const float* W0   = (const float*)d_in[8];
  const float* b0   = (const float*)d_in[9];
  const float* W1   = (const float*)d_in[10];
  const float* b1   = (const float*)d_in[11];
  const float* W2   = (const float*)d_in[12];
  const float* b2   = (const float*)d_in[13];

  char* wsb = (char*)d_ws;
  size_t off = 0;
  auto alloc = [&](size_t bytes){
    size_t r = off;
    off += (bytes + 255) & ~(size_t)255;
    return r;
  };
  ushort_t* MSW = (ushort_t*)(wsb + alloc((size_t)TR*HID*2));
  ushort_t* QSW = (ushort_t*)(wsb + alloc((size_t)TR*HID*2));
  ushort_t* GT  = (ushort_t*)(wsb + alloc((size_t)TR*LBL*2));
  ushort_t* W1B = (ushort_t*)(wsb + alloc((size_t)TR*TR*2));
  float*    KV  = (float*)   (wsb + alloc((size_t)TR*4));
  ushort_t* U   = (ushort_t*)(wsb + alloc((size_t)BATCH*TR*2));
  (void)ws_size; (void)in_sizes; (void)n_in; (void)out_size;

  k1<<<257, 256, 0, stream>>>(W0, Wt, Wl, bt, bl, b0, W1, MSW, QSW, W1B, KV, (float*)d_out);
  k2<<<1056, 256, 0, stream>>>(labe, QSW, text, MSW, KV, GT, U);
  k3<<<BATCH/16, 256, 0, stream>>>(U, GT, tgt, perm, W1B, b1, W2, b2, (float*)d_out);
}